// Round 1
// baseline (369.418 us; speedup 1.0000x reference)
//
#include <hip/hip_runtime.h>

// Problem constants
#define DIN   512
#define TSEQ  2048
#define BATCH 4
#define NH    8
#define DHEAD 64
#define MTOT  8192   // BATCH*TSEQ

typedef __attribute__((ext_vector_type(8))) __bf16 bf16x8;
typedef __attribute__((ext_vector_type(8))) short  s16x8;
typedef __attribute__((ext_vector_type(4))) float  f32x4;

__device__ __forceinline__ unsigned short f2b(float f) {
  union { float f; unsigned int u; } c; c.f = f;
  unsigned int r = (c.u + 0x7fffu + ((c.u >> 16) & 1u)) >> 16;
  return (unsigned short)r;
}

__device__ __forceinline__ f32x4 mfma16(bf16x8 a, bf16x8 b, f32x4 c) {
  return __builtin_amdgcn_mfma_f32_16x16x32_bf16(a, b, c, 0, 0, 0);
}

// ---------------------------------------------------------------- cast fp32 -> bf16
__global__ __launch_bounds__(256) void cast_kernel(const float* __restrict__ in,
                                                   unsigned short* __restrict__ out, int n) {
  int i = (blockIdx.x * 256 + threadIdx.x) * 4;
  if (i < n) {
    float4 v = *(const float4*)(in + i);
    ushort4 o;
    o.x = f2b(v.x); o.y = f2b(v.y); o.z = f2b(v.z); o.w = f2b(v.w);
    *(ushort4*)(out + i) = o;
  }
}

// ------------------------------------------- W [K][N] fp32 -> Wt [N][K] bf16
__global__ __launch_bounds__(256) void transpose_cast_kernel(const float* __restrict__ W,
                                                             unsigned short* __restrict__ Wt) {
  __shared__ float tile[32][33];
  int bx = blockIdx.x * 32;  // n range
  int by = blockIdx.y * 32;  // k range
  int tx = threadIdx.x & 31, ty = threadIdx.x >> 5;  // 256 thr: ty 0..7
  #pragma unroll
  for (int yy = ty; yy < 32; yy += 8)
    tile[yy][tx] = W[(size_t)(by + yy) * DIN + bx + tx];
  __syncthreads();
  #pragma unroll
  for (int yy = ty; yy < 32; yy += 8)
    Wt[(size_t)(bx + yy) * DIN + by + tx] = f2b(tile[tx][yy]);
}

// ---------------------------------------------------------------- GEMM
// C[M][512] = A[M][512](bf16) @ Bt[512][512]^T(bf16, stored [N][K]) + bias, + epilogue
enum { EPI_BF16 = 0, EPI_VT = 1, EPI_F32RES = 2, EPI_LRELU = 3 };

template <int EPI>
__global__ __launch_bounds__(256) void gemm_kernel(const unsigned short* __restrict__ A,
                                                   const unsigned short* __restrict__ Bt,
                                                   const float* __restrict__ bias,
                                                   const float* __restrict__ res,
                                                   void* __restrict__ out) {
  __shared__ unsigned short Als[128 * 40];  // [128 rows][32 k] pad to 40
  __shared__ unsigned short Bls[128 * 40];
  const int tid = threadIdx.x;
  const int lane = tid & 63, wid = tid >> 6;
  const int wr = wid >> 1, wc = wid & 1;
  const int l15 = lane & 15, lg = lane >> 4;
  const int m0 = blockIdx.x * 128;
  const int n0 = blockIdx.y * 128;

  f32x4 acc[4][4] = {};

  for (int k0 = 0; k0 < 512; k0 += 32) {
    __syncthreads();
    #pragma unroll
    for (int i = 0; i < 2; ++i) {
      int ci = tid + i * 256;          // 0..511
      int row = ci >> 2, cx = ci & 3;  // [128][4 x 16B]
      s16x8 va = *(const s16x8*)(A + (size_t)(m0 + row) * 512 + k0 + cx * 8);
      *(s16x8*)(&Als[row * 40 + cx * 8]) = va;
      s16x8 vb = *(const s16x8*)(Bt + (size_t)(n0 + row) * 512 + k0 + cx * 8);
      *(s16x8*)(&Bls[row * 40 + cx * 8]) = vb;
    }
    __syncthreads();
    bf16x8 af[4], bfr[4];
    #pragma unroll
    for (int m = 0; m < 4; ++m)
      af[m] = *(const bf16x8*)(&Als[(wr * 64 + m * 16 + l15) * 40 + lg * 8]);
    #pragma unroll
    for (int n = 0; n < 4; ++n)
      bfr[n] = *(const bf16x8*)(&Bls[(wc * 64 + n * 16 + l15) * 40 + lg * 8]);
    #pragma unroll
    for (int m = 0; m < 4; ++m)
      #pragma unroll
      for (int n = 0; n < 4; ++n)
        acc[m][n] = mfma16(af[m], bfr[n], acc[m][n]);
  }

  // epilogue: C/D layout: col = l15, row = lg*4 + reg
  #pragma unroll
  for (int m = 0; m < 4; ++m) {
    int grb = m0 + wr * 64 + m * 16 + lg * 4;
    #pragma unroll
    for (int n = 0; n < 4; ++n) {
      int gc = n0 + wc * 64 + n * 16 + l15;
      float bv = bias[gc];
      #pragma unroll
      for (int r = 0; r < 4; ++r) {
        int gr = grb + r;
        float v = acc[m][n][r] + bv;
        if (EPI == EPI_F32RES) {
          ((float*)out)[(size_t)gr * 512 + gc] = v + res[(size_t)gr * 512 + gc];
        } else if (EPI == EPI_BF16) {
          ((unsigned short*)out)[(size_t)gr * 512 + gc] = f2b(v);
        } else if (EPI == EPI_LRELU) {
          v = v > 0.f ? v : 0.01f * v;
          ((unsigned short*)out)[(size_t)gr * 512 + gc] = f2b(v);
        } else {  // EPI_VT: gr = b*2048+t, gc = h*64+d -> Vt[(b*512+gc)][t]
          int b = gr >> 11, t = gr & 2047;
          ((unsigned short*)out)[((size_t)(b * 512 + gc) << 11) + t] = f2b(v);
        }
      }
    }
  }
}

// ---------------------------------------------------------------- flash attention
// Q,K: [8192][512] bf16 (per-head cols h*64..), Vt: [B*512][2048] bf16 ([b][h][d][t])
// O: [8192][512] bf16. Causal. scale 1/8.
__global__ __launch_bounds__(256) void attn_kernel(const unsigned short* __restrict__ Q,
                                                   const unsigned short* __restrict__ K,
                                                   const unsigned short* __restrict__ Vt,
                                                   unsigned short* __restrict__ O) {
  __shared__ unsigned short Kls[64 * 72];
  __shared__ unsigned short Vls[64 * 72];
  __shared__ unsigned short Pls[4 * 16 * 72];
  const int tid = threadIdx.x, lane = tid & 63, w = tid >> 6;
  const int l15 = lane & 15, lg = lane >> 4;
  const int qb = blockIdx.x;   // q block of 64
  const int bh = blockIdx.y;   // b*8+h
  const int b = bh >> 3, h = bh & 7;
  const int q0 = qb * 64 + w * 16;  // wave's 16 q rows

  bf16x8 qf[2];
  #pragma unroll
  for (int kf = 0; kf < 2; ++kf)
    qf[kf] = *(const bf16x8*)(Q + (size_t)(b * 2048 + q0 + l15) * 512 + h * 64 + kf * 32 + lg * 8);

  float mrun[4], lrun[4];
  f32x4 o[4] = {};
  #pragma unroll
  for (int r = 0; r < 4; ++r) { mrun[r] = -1e30f; lrun[r] = 0.f; }

  for (int kb = 0; kb <= qb; ++kb) {
    const int kv0 = kb * 64;
    __syncthreads();
    #pragma unroll
    for (int i = 0; i < 2; ++i) {
      int ci = tid + i * 256;          // 0..511
      int row = ci >> 3, cx = ci & 7;  // [64][8 x 16B]
      s16x8 kvv = *(const s16x8*)(K + (size_t)(b * 2048 + kv0 + row) * 512 + h * 64 + cx * 8);
      *(s16x8*)(&Kls[row * 72 + cx * 8]) = kvv;
      s16x8 vv = *(const s16x8*)(Vt + (size_t)(b * 512 + h * 64 + row) * 2048 + kv0 + cx * 8);
      *(s16x8*)(&Vls[row * 72 + cx * 8]) = vv;
    }
    __syncthreads();

    // S = Q K^T : D row = q (lg*4+r), col = kv (l15), tiles t over kv
    f32x4 st[4];
    #pragma unroll
    for (int t = 0; t < 4; ++t) {
      st[t] = f32x4{0.f, 0.f, 0.f, 0.f};
      #pragma unroll
      for (int kf = 0; kf < 2; ++kf) {
        bf16x8 kfr = *(const bf16x8*)(&Kls[(t * 16 + l15) * 72 + kf * 32 + lg * 8]);
        st[t] = mfma16(qf[kf], kfr, st[t]);
      }
    }
    const bool diag = (kb == qb);
    #pragma unroll
    for (int t = 0; t < 4; ++t)
      #pragma unroll
      for (int r = 0; r < 4; ++r) {
        float v = st[t][r] * 0.125f;
        if (diag) {
          int kvl = t * 16 + l15, ql = w * 16 + lg * 4 + r;
          if (kvl > ql) v = -1e30f;
        }
        st[t][r] = v;
      }

    // online softmax, rows live on (lg, r); reduce across 16 lanes sharing lg
    #pragma unroll
    for (int r = 0; r < 4; ++r) {
      float mx = fmaxf(fmaxf(st[0][r], st[1][r]), fmaxf(st[2][r], st[3][r]));
      #pragma unroll
      for (int s = 1; s < 16; s <<= 1) mx = fmaxf(mx, __shfl_xor(mx, s, 64));
      float nm = fmaxf(mrun[r], mx);
      float alpha = __expf(mrun[r] - nm);
      mrun[r] = nm;
      float rs = 0.f;
      #pragma unroll
      for (int t = 0; t < 4; ++t) {
        float p = __expf(st[t][r] - nm);
        st[t][r] = p;
        rs += p;
      }
      #pragma unroll
      for (int s = 1; s < 16; s <<= 1) rs += __shfl_xor(rs, s, 64);
      lrun[r] = lrun[r] * alpha + rs;
      #pragma unroll
      for (int n = 0; n < 4; ++n) o[n][r] *= alpha;
    }

    // P -> LDS (transpose to A-operand layout), then PV
    #pragma unroll
    for (int t = 0; t < 4; ++t)
      #pragma unroll
      for (int r = 0; r < 4; ++r)
        Pls[w * 1152 + (lg * 4 + r) * 72 + t * 16 + l15] = f2b(st[t][r]);

    #pragma unroll
    for (int kf = 0; kf < 2; ++kf) {
      bf16x8 pa = *(const bf16x8*)(&Pls[w * 1152 + l15 * 72 + kf * 32 + lg * 8]);
      #pragma unroll
      for (int n = 0; n < 4; ++n) {
        bf16x8 vf = *(const bf16x8*)(&Vls[(n * 16 + l15) * 72 + kf * 32 + lg * 8]);
        o[n] = mfma16(pa, vf, o[n]);
      }
    }
  }

  #pragma unroll
  for (int n = 0; n < 4; ++n)
    #pragma unroll
    for (int r = 0; r < 4; ++r) {
      float v = o[n][r] / lrun[r];
      O[(size_t)(b * 2048 + q0 + lg * 4 + r) * 512 + h * 64 + n * 16 + l15] = f2b(v);
    }
}

// ---------------------------------------------------------------- LayerNorm (wave per row)
template <int WRITE_BF16>
__global__ __launch_bounds__(256) void ln_kernel(const float* __restrict__ X,
                                                 const float* __restrict__ g,
                                                 const float* __restrict__ be,
                                                 float* __restrict__ Yf,
                                                 unsigned short* __restrict__ Yb) {
  int row = blockIdx.x * 4 + (threadIdx.x >> 6);
  int lane = threadIdx.x & 63;
  const float* x = X + (size_t)row * 512;
  float4 v0 = *(const float4*)(x + lane * 4);
  float4 v1 = *(const float4*)(x + 256 + lane * 4);
  float s = v0.x + v0.y + v0.z + v0.w + v1.x + v1.y + v1.z + v1.w;
  #pragma unroll
  for (int t = 1; t < 64; t <<= 1) s += __shfl_xor(s, t, 64);
  float mu = s * (1.f / 512.f);
  float q = 0.f;
  q += (v0.x - mu) * (v0.x - mu); q += (v0.y - mu) * (v0.y - mu);
  q += (v0.z - mu) * (v0.z - mu); q += (v0.w - mu) * (v0.w - mu);
  q += (v1.x - mu) * (v1.x - mu); q += (v1.y - mu) * (v1.y - mu);
  q += (v1.z - mu) * (v1.z - mu); q += (v1.w - mu) * (v1.w - mu);
  #pragma unroll
  for (int t = 1; t < 64; t <<= 1) q += __shfl_xor(q, t, 64);
  float rstd = rsqrtf(q * (1.f / 512.f) + 1e-5f);

  float4 g0 = *(const float4*)(g + lane * 4);
  float4 g1 = *(const float4*)(g + 256 + lane * 4);
  float4 b0 = *(const float4*)(be + lane * 4);
  float4 b1 = *(const float4*)(be + 256 + lane * 4);
  float4 y0, y1;
  y0.x = (v0.x - mu) * rstd * g0.x + b0.x; y0.y = (v0.y - mu) * rstd * g0.y + b0.y;
  y0.z = (v0.z - mu) * rstd * g0.z + b0.z; y0.w = (v0.w - mu) * rstd * g0.w + b0.w;
  y1.x = (v1.x - mu) * rstd * g1.x + b1.x; y1.y = (v1.y - mu) * rstd * g1.y + b1.y;
  y1.z = (v1.z - mu) * rstd * g1.z + b1.z; y1.w = (v1.w - mu) * rstd * g1.w + b1.w;
  if (Yf) {
    *(float4*)(Yf + (size_t)row * 512 + lane * 4) = y0;
    *(float4*)(Yf + (size_t)row * 512 + 256 + lane * 4) = y1;
  }
  if (WRITE_BF16) {
    ushort4 u0, u1;
    u0.x = f2b(y0.x); u0.y = f2b(y0.y); u0.z = f2b(y0.z); u0.w = f2b(y0.w);
    u1.x = f2b(y1.x); u1.y = f2b(y1.y); u1.z = f2b(y1.z); u1.w = f2b(y1.w);
    *(ushort4*)(Yb + (size_t)row * 512 + lane * 4) = u0;
    *(ushort4*)(Yb + (size_t)row * 512 + 256 + lane * 4) = u1;
  }
}

// ---------------------------------------------------------------- launch
extern "C" void kernel_launch(void* const* d_in, const int* in_sizes, int n_in,
                              void* d_out, int out_size, void* d_ws, size_t ws_size,
                              hipStream_t stream) {
  const float* q_in = (const float*)d_in[0];
  const float* k_in = (const float*)d_in[1];
  const float* v_in = (const float*)d_in[2];
  const float* Wq = (const float*)d_in[3];  const float* bq = (const float*)d_in[4];
  const float* Wk = (const float*)d_in[5];  const float* bk = (const float*)d_in[6];
  const float* Wv = (const float*)d_in[7];  const float* bv = (const float*)d_in[8];
  const float* Wo = (const float*)d_in[9];  const float* bo = (const float*)d_in[10];
  const float* Wh = (const float*)d_in[11]; const float* bh = (const float*)d_in[12];
  const float* W2 = (const float*)d_in[13]; const float* b2 = (const float*)d_in[14];
  const float* g1 = (const float*)d_in[15]; const float* be1 = (const float*)d_in[16];
  const float* g2 = (const float*)d_in[17]; const float* be2 = (const float*)d_in[18];

  char* ws = (char*)d_ws;
  const size_t MD2 = (size_t)MTOT * 512 * 2;   // 8 MB bf16 buffer
  const size_t W1  = (size_t)512 * 512 * 2;    // one bf16 weight
  const size_t MD4 = (size_t)MTOT * 512 * 4;   // 16 MB f32 buffer
  unsigned short* qb_  = (unsigned short*)(ws);
  unsigned short* kb_  = (unsigned short*)(ws + MD2);
  unsigned short* vb_  = (unsigned short*)(ws + 2 * MD2);
  unsigned short* Qp   = (unsigned short*)(ws + 3 * MD2);
  unsigned short* Kp   = (unsigned short*)(ws + 4 * MD2);
  unsigned short* Vt   = (unsigned short*)(ws + 5 * MD2);
  unsigned short* Wt   = (unsigned short*)(ws + 6 * MD2);  // 6 matrices
  float*          hy   = (float*)(ws + 6 * MD2 + 6 * W1);
  float*          ln1f = (float*)(ws + 6 * MD2 + 6 * W1 + MD4);
  // buffer reuse after their consumers are done:
  unsigned short* attn = qb_;   // after GEMM(Qp) consumed qb_
  unsigned short* ln1b = kb_;
  unsigned short* f1   = vb_;

  const int NELEM = MTOT * 512;
  // casts
  cast_kernel<<<NELEM / 1024, 256, 0, stream>>>(q_in, qb_, NELEM);
  cast_kernel<<<NELEM / 1024, 256, 0, stream>>>(k_in, kb_, NELEM);
  cast_kernel<<<NELEM / 1024, 256, 0, stream>>>(v_in, vb_, NELEM);
  // weight transposes: [K][N] -> [N][K] bf16
  dim3 tg(16, 16);
  transpose_cast_kernel<<<tg, 256, 0, stream>>>(Wq, Wt + 0 * 512 * 512);
  transpose_cast_kernel<<<tg, 256, 0, stream>>>(Wk, Wt + 1 * 512 * 512);
  transpose_cast_kernel<<<tg, 256, 0, stream>>>(Wv, Wt + 2 * 512 * 512);
  transpose_cast_kernel<<<tg, 256, 0, stream>>>(Wo, Wt + 3 * 512 * 512);
  transpose_cast_kernel<<<tg, 256, 0, stream>>>(Wh, Wt + 4 * 512 * 512);
  transpose_cast_kernel<<<tg, 256, 0, stream>>>(W2, Wt + 5 * 512 * 512);

  dim3 gg(MTOT / 128, 512 / 128);
  // projections
  gemm_kernel<EPI_BF16><<<gg, 256, 0, stream>>>(qb_, Wt + 0 * 512 * 512, bq, nullptr, Qp);
  gemm_kernel<EPI_BF16><<<gg, 256, 0, stream>>>(kb_, Wt + 1 * 512 * 512, bk, nullptr, Kp);
  gemm_kernel<EPI_VT><<<gg, 256, 0, stream>>>(vb_, Wt + 2 * 512 * 512, bv, nullptr, Vt);
  // attention
  dim3 ag(TSEQ / 64, BATCH * NH);
  attn_kernel<<<ag, 256, 0, stream>>>(Qp, Kp, Vt, attn);
  // h = attn @ Wo + bo + q
  gemm_kernel<EPI_F32RES><<<gg, 256, 0, stream>>>(attn, Wt + 3 * 512 * 512, bo, q_in, hy);
  // LN1 -> bf16 + f32
  ln_kernel<1><<<MTOT / 4, 256, 0, stream>>>(hy, g1, be1, ln1f, ln1b);
  // f1 = leaky(ln1 @ Wh + bh)
  gemm_kernel<EPI_LRELU><<<gg, 256, 0, stream>>>(ln1b, Wt + 4 * 512 * 512, bh, nullptr, f1);
  // y = f1 @ W2 + b2 + ln1
  gemm_kernel<EPI_F32RES><<<gg, 256, 0, stream>>>(f1, Wt + 5 * 512 * 512, b2, ln1f, hy);
  // LN2 -> out (fp32)
  ln_kernel<0><<<MTOT / 4, 256, 0, stream>>>(hy, g2, be2, (float*)d_out, nullptr);
}

// Round 2
// 331.035 us; speedup vs baseline: 1.1159x; 1.1159x over previous
//
#include <hip/hip_runtime.h>

// Problem constants
#define DIN   512
#define TSEQ  2048
#define BATCH 4
#define NH    8
#define DHEAD 64
#define MTOT  8192   // BATCH*TSEQ

typedef __attribute__((ext_vector_type(8))) __bf16 bf16x8;
typedef __attribute__((ext_vector_type(8))) short  s16x8;
typedef __attribute__((ext_vector_type(4))) float  f32x4;

__device__ __forceinline__ unsigned short f2b(float f) {
  union { float f; unsigned int u; } c; c.f = f;
  unsigned int r = (c.u + 0x7fffu + ((c.u >> 16) & 1u)) >> 16;
  return (unsigned short)r;
}

// pack two floats -> 2 bf16 in one u32 (compiler emits v_cvt_pk_bf16_f32)
__device__ __forceinline__ unsigned int pkbf(float a, float b) {
  union { __bf16 h[2]; unsigned int u; } c;
  c.h[0] = (__bf16)a; c.h[1] = (__bf16)b; return c.u;
}

__device__ __forceinline__ f32x4 mfma16(bf16x8 a, bf16x8 b, f32x4 c) {
  return __builtin_amdgcn_mfma_f32_16x16x32_bf16(a, b, c, 0, 0, 0);
}

// ------------------------------------------- W [K][N] fp32 -> Wt [N][K] bf16
__global__ __launch_bounds__(256) void transpose_cast_kernel(const float* __restrict__ W,
                                                             unsigned short* __restrict__ Wt) {
  __shared__ float tile[32][33];
  int bx = blockIdx.x * 32;  // n range
  int by = blockIdx.y * 32;  // k range
  int tx = threadIdx.x & 31, ty = threadIdx.x >> 5;  // 256 thr: ty 0..7
  #pragma unroll
  for (int yy = ty; yy < 32; yy += 8)
    tile[yy][tx] = W[(size_t)(by + yy) * DIN + bx + tx];
  __syncthreads();
  #pragma unroll
  for (int yy = ty; yy < 32; yy += 8)
    Wt[(size_t)(bx + yy) * DIN + by + tx] = f2b(tile[tx][yy]);
}

// ---------------------------------------------------------------- GEMM
// C[M][512] = A[M][512] @ Bt[512][512]^T(bf16, stored [N][K]) + bias, + epilogue
// BM=64, BN=128, BK=64; 4 waves (2x2), per-wave 32x64, acc 2x4.
enum { EPI_BF16 = 0, EPI_VT = 1, EPI_F32RES = 2, EPI_LRELU = 3 };

template <int EPI, int AF32>
__global__ __launch_bounds__(256) void gemm_kernel(const void* __restrict__ Ain,
                                                   const unsigned short* __restrict__ Bt,
                                                   const float* __restrict__ bias,
                                                   const float* __restrict__ res,
                                                   void* __restrict__ out) {
  __shared__ unsigned short Als[64 * 72];   // [64 rows][64 k] pad to 72
  __shared__ unsigned short Bls[128 * 72];
  const int tid = threadIdx.x;
  const int lane = tid & 63, wid = tid >> 6;
  const int wr = wid >> 1, wc = wid & 1;
  const int l = lane & 15, g = lane >> 4;
  const int m0 = blockIdx.x * 64;
  const int n0 = blockIdx.y * 128;

  f32x4 acc[2][4] = {};

  for (int k0 = 0; k0 < 512; k0 += 64) {
    __syncthreads();
    if (AF32) {
      const float* Af = (const float*)Ain;
      #pragma unroll
      for (int i = 0; i < 4; ++i) {
        int c = tid + i * 256;             // 0..1023 float4 chunks
        int row = c >> 4, cx = c & 15;     // [64 rows][16 x float4]
        float4 v = *(const float4*)(Af + (size_t)(m0 + row) * 512 + k0 + cx * 4);
        ushort4 u;
        u.x = f2b(v.x); u.y = f2b(v.y); u.z = f2b(v.z); u.w = f2b(v.w);
        *(ushort4*)(&Als[row * 72 + cx * 4]) = u;
      }
    } else {
      const unsigned short* Ab = (const unsigned short*)Ain;
      #pragma unroll
      for (int i = 0; i < 2; ++i) {
        int c = tid + i * 256;             // 0..511 16B chunks
        int row = c >> 3, cx = c & 7;      // [64 rows][8 x 16B]
        *(s16x8*)(&Als[row * 72 + cx * 8]) =
            *(const s16x8*)(Ab + (size_t)(m0 + row) * 512 + k0 + cx * 8);
      }
    }
    #pragma unroll
    for (int i = 0; i < 4; ++i) {
      int c = tid + i * 256;               // 0..1023 16B chunks
      int row = c >> 3, cx = c & 7;        // [128 rows][8 x 16B]
      *(s16x8*)(&Bls[row * 72 + cx * 8]) =
          *(const s16x8*)(Bt + (size_t)(n0 + row) * 512 + k0 + cx * 8);
    }
    __syncthreads();
    #pragma unroll
    for (int kk = 0; kk < 2; ++kk) {
      bf16x8 af[2], bfr[4];
      #pragma unroll
      for (int m = 0; m < 2; ++m)
        af[m] = *(const bf16x8*)(&Als[(wr * 32 + m * 16 + l) * 72 + kk * 32 + g * 8]);
      #pragma unroll
      for (int n = 0; n < 4; ++n)
        bfr[n] = *(const bf16x8*)(&Bls[(wc * 64 + n * 16 + l) * 72 + kk * 32 + g * 8]);
      #pragma unroll
      for (int m = 0; m < 2; ++m)
        #pragma unroll
        for (int n = 0; n < 4; ++n)
          acc[m][n] = mfma16(af[m], bfr[n], acc[m][n]);
    }
  }

  // epilogue: C/D layout: col = l, row = g*4 + r
  #pragma unroll
  for (int m = 0; m < 2; ++m) {
    int grb = m0 + wr * 32 + m * 16 + g * 4;
    #pragma unroll
    for (int n = 0; n < 4; ++n) {
      int gc = n0 + wc * 64 + n * 16 + l;
      float bv = bias[gc];
      #pragma unroll
      for (int r = 0; r < 4; ++r) {
        int gr = grb + r;
        float v = acc[m][n][r] + bv;
        if (EPI == EPI_F32RES) {
          ((float*)out)[(size_t)gr * 512 + gc] = v + res[(size_t)gr * 512 + gc];
        } else if (EPI == EPI_BF16) {
          ((unsigned short*)out)[(size_t)gr * 512 + gc] = f2b(v);
        } else if (EPI == EPI_LRELU) {
          v = v > 0.f ? v : 0.01f * v;
          ((unsigned short*)out)[(size_t)gr * 512 + gc] = f2b(v);
        } else {  // EPI_VT: gr = b*2048+t, gc = h*64+d -> Vt[(b*512+gc)][t]
          int b = gr >> 11, t = gr & 2047;
          ((unsigned short*)out)[((size_t)(b * 512 + gc) << 11) + t] = f2b(v);
        }
      }
    }
  }
}

// ---------------------------------------------------------------- flash attention
// Swapped QK^T: st = mfma(K, Q) -> lane owns one q row (l = lane&15), 16 scores.
// Q,K: [8192][512] bf16, Vt: [B*512][2048] bf16 ([b][h][d][t]), O: [8192][512] bf16.
__global__ __launch_bounds__(256) void attn_kernel(const unsigned short* __restrict__ Q,
                                                   const unsigned short* __restrict__ K,
                                                   const unsigned short* __restrict__ Vt,
                                                   unsigned short* __restrict__ O) {
  __shared__ unsigned short Kls[64 * 72];
  __shared__ unsigned short Vls[64 * 72];
  __shared__ unsigned short Pls[4][16 * 68];  // per-wave P tile [16 q rows][64 kv] pad 68
  const int tid = threadIdx.x, lane = tid & 63, w = tid >> 6;
  const int l = lane & 15, g = lane >> 4;
  const int qb = (int)gridDim.x - 1 - (int)blockIdx.x;  // longest blocks first
  const int bh = blockIdx.y;
  const int b = bh >> 3, h = bh & 7;
  const int q0 = qb * 64 + w * 16;  // wave's 16 q rows

  bf16x8 qf[2];
  #pragma unroll
  for (int kf = 0; kf < 2; ++kf)
    qf[kf] = *(const bf16x8*)(Q + (size_t)(b * 2048 + q0 + l) * 512 + h * 64 + kf * 32 + g * 8);

  float mrun = -1e30f, lrun = 0.f;   // per-lane: q row = q0 + l
  f32x4 o[4] = {};                    // O rows q0+g*4+r, cols n*16+l

  for (int kb = 0; kb <= qb; ++kb) {
    const int kv0 = kb * 64;
    __syncthreads();
    #pragma unroll
    for (int i = 0; i < 2; ++i) {
      int ci = tid + i * 256;          // 0..511
      int row = ci >> 3, cx = ci & 7;  // [64][8 x 16B]
      *(s16x8*)(&Kls[row * 72 + cx * 8]) =
          *(const s16x8*)(K + (size_t)(b * 2048 + kv0 + row) * 512 + h * 64 + cx * 8);
      *(s16x8*)(&Vls[row * 72 + cx * 8]) =
          *(const s16x8*)(Vt + (size_t)(b * 512 + h * 64 + row) * 2048 + kv0 + cx * 8);
    }
    __syncthreads();

    // S^T: lane holds S[q=q0+l][kv = kv0 + t*16 + g*4 + r]
    f32x4 st[4];
    #pragma unroll
    for (int t = 0; t < 4; ++t) {
      st[t] = f32x4{0.f, 0.f, 0.f, 0.f};
      #pragma unroll
      for (int kf = 0; kf < 2; ++kf) {
        bf16x8 kfr = *(const bf16x8*)(&Kls[(t * 16 + l) * 72 + kf * 32 + g * 8]);
        st[t] = mfma16(kfr, qf[kf], st[t]);
      }
    }
    const bool diag = (kb == qb);
    const int qrow = q0 + l;
    #pragma unroll
    for (int t = 0; t < 4; ++t)
      #pragma unroll
      for (int r = 0; r < 4; ++r) {
        float v = st[t][r] * 0.125f;
        if (diag && (kv0 + t * 16 + g * 4 + r > qrow)) v = -1e30f;
        st[t][r] = v;
      }

    // per-lane row softmax (+2-shfl reduce across the 4 g-lanes of this row)
    float mx = fmaxf(fmaxf(fmaxf(st[0][0], st[0][1]), fmaxf(st[0][2], st[0][3])),
                     fmaxf(fmaxf(st[1][0], st[1][1]), fmaxf(st[1][2], st[1][3])));
    mx = fmaxf(mx, fmaxf(fmaxf(fmaxf(st[2][0], st[2][1]), fmaxf(st[2][2], st[2][3])),
                         fmaxf(fmaxf(st[3][0], st[3][1]), fmaxf(st[3][2], st[3][3]))));
    mx = fmaxf(mx, __shfl_xor(mx, 16, 64));
    mx = fmaxf(mx, __shfl_xor(mx, 32, 64));
    float nm = fmaxf(mrun, mx);
    float alpha = __expf(mrun - nm);
    mrun = nm;
    float rs = 0.f;
    #pragma unroll
    for (int t = 0; t < 4; ++t)
      #pragma unroll
      for (int r = 0; r < 4; ++r) {
        float p = __expf(st[t][r] - nm);
        st[t][r] = p;
        rs += p;
      }
    rs += __shfl_xor(rs, 16, 64);
    rs += __shfl_xor(rs, 32, 64);
    lrun = lrun * alpha + rs;

    // rescale O: o[n][r] row q0+g*4+r needs alpha from lane (g*4+r)
    #pragma unroll
    for (int r = 0; r < 4; ++r) {
      float ar = __shfl(alpha, g * 4 + r, 64);
      #pragma unroll
      for (int n = 0; n < 4; ++n) o[n][r] *= ar;
    }

    // pack P row to bf16, write [q=l][kv] (b64 stores), read back as PV A-frags
    char* prow = (char*)&Pls[w][0] + l * 136;
    #pragma unroll
    for (int t = 0; t < 4; ++t) {
      uint2 u;
      u.x = pkbf(st[t][0], st[t][1]);
      u.y = pkbf(st[t][2], st[t][3]);
      *(uint2*)(prow + t * 32 + g * 8) = u;
    }
    #pragma unroll
    for (int kf = 0; kf < 2; ++kf) {
      bf16x8 pa = *(const bf16x8*)((char*)&Pls[w][0] + l * 136 + kf * 64 + g * 16);
      #pragma unroll
      for (int n = 0; n < 4; ++n) {
        bf16x8 vf = *(const bf16x8*)(&Vls[(n * 16 + l) * 72 + kf * 32 + g * 8]);
        o[n] = mfma16(pa, vf, o[n]);
      }
    }
  }

  float li = 1.f / lrun;
  #pragma unroll
  for (int r = 0; r < 4; ++r) {
    float lir = __shfl(li, g * 4 + r, 64);
    #pragma unroll
    for (int n = 0; n < 4; ++n)
      O[(size_t)(b * 2048 + q0 + g * 4 + r) * 512 + h * 64 + n * 16 + l] =
          f2b(o[n][r] * lir);
  }
}

// ---------------------------------------------------------------- LayerNorm (wave per row)
template <int WRITE_BF16>
__global__ __launch_bounds__(256) void ln_kernel(const float* __restrict__ X,
                                                 const float* __restrict__ g,
                                                 const float* __restrict__ be,
                                                 float* __restrict__ Yf,
                                                 unsigned short* __restrict__ Yb) {
  int row = blockIdx.x * 4 + (threadIdx.x >> 6);
  int lane = threadIdx.x & 63;
  const float* x = X + (size_t)row * 512;
  float4 v0 = *(const float4*)(x + lane * 4);
  float4 v1 = *(const float4*)(x + 256 + lane * 4);
  float s = v0.x + v0.y + v0.z + v0.w + v1.x + v1.y + v1.z + v1.w;
  #pragma unroll
  for (int t = 1; t < 64; t <<= 1) s += __shfl_xor(s, t, 64);
  float mu = s * (1.f / 512.f);
  float q = 0.f;
  q += (v0.x - mu) * (v0.x - mu); q += (v0.y - mu) * (v0.y - mu);
  q += (v0.z - mu) * (v0.z - mu); q += (v0.w - mu) * (v0.w - mu);
  q += (v1.x - mu) * (v1.x - mu); q += (v1.y - mu) * (v1.y - mu);
  q += (v1.z - mu) * (v1.z - mu); q += (v1.w - mu) * (v1.w - mu);
  #pragma unroll
  for (int t = 1; t < 64; t <<= 1) q += __shfl_xor(q, t, 64);
  float rstd = rsqrtf(q * (1.f / 512.f) + 1e-5f);

  float4 g0 = *(const float4*)(g + lane * 4);
  float4 g1 = *(const float4*)(g + 256 + lane * 4);
  float4 b0 = *(const float4*)(be + lane * 4);
  float4 b1 = *(const float4*)(be + 256 + lane * 4);
  float4 y0, y1;
  y0.x = (v0.x - mu) * rstd * g0.x + b0.x; y0.y = (v0.y - mu) * rstd * g0.y + b0.y;
  y0.z = (v0.z - mu) * rstd * g0.z + b0.z; y0.w = (v0.w - mu) * rstd * g0.w + b0.w;
  y1.x = (v1.x - mu) * rstd * g1.x + b1.x; y1.y = (v1.y - mu) * rstd * g1.y + b1.y;
  y1.z = (v1.z - mu) * rstd * g1.z + b1.z; y1.w = (v1.w - mu) * rstd * g1.w + b1.w;
  if (Yf) {
    *(float4*)(Yf + (size_t)row * 512 + lane * 4) = y0;
    *(float4*)(Yf + (size_t)row * 512 + 256 + lane * 4) = y1;
  }
  if (WRITE_BF16) {
    ushort4 u0, u1;
    u0.x = f2b(y0.x); u0.y = f2b(y0.y); u0.z = f2b(y0.z); u0.w = f2b(y0.w);
    u1.x = f2b(y1.x); u1.y = f2b(y1.y); u1.z = f2b(y1.z); u1.w = f2b(y1.w);
    *(ushort4*)(Yb + (size_t)row * 512 + lane * 4) = u0;
    *(ushort4*)(Yb + (size_t)row * 512 + 256 + lane * 4) = u1;
  }
}

// ---------------------------------------------------------------- launch
extern "C" void kernel_launch(void* const* d_in, const int* in_sizes, int n_in,
                              void* d_out, int out_size, void* d_ws, size_t ws_size,
                              hipStream_t stream) {
  const float* q_in = (const float*)d_in[0];
  const float* k_in = (const float*)d_in[1];
  const float* v_in = (const float*)d_in[2];
  const float* Wq = (const float*)d_in[3];  const float* bq = (const float*)d_in[4];
  const float* Wk = (const float*)d_in[5];  const float* bk = (const float*)d_in[6];
  const float* Wv = (const float*)d_in[7];  const float* bv = (const float*)d_in[8];
  const float* Wo = (const float*)d_in[9];  const float* bo = (const float*)d_in[10];
  const float* Wh = (const float*)d_in[11]; const float* bh = (const float*)d_in[12];
  const float* W2 = (const float*)d_in[13]; const float* b2 = (const float*)d_in[14];
  const float* g1 = (const float*)d_in[15]; const float* be1 = (const float*)d_in[16];
  const float* g2 = (const float*)d_in[17]; const float* be2 = (const float*)d_in[18];

  char* ws = (char*)d_ws;
  const size_t MD2 = (size_t)MTOT * 512 * 2;   // 8 MB bf16 buffer
  const size_t W1  = (size_t)512 * 512 * 2;    // one bf16 weight
  const size_t MD4 = (size_t)MTOT * 512 * 4;   // 16 MB f32 buffer
  unsigned short* Qp   = (unsigned short*)(ws);
  unsigned short* Kp   = (unsigned short*)(ws + MD2);
  unsigned short* Vt   = (unsigned short*)(ws + 2 * MD2);
  unsigned short* attn = (unsigned short*)(ws + 3 * MD2);
  unsigned short* Wt   = (unsigned short*)(ws + 4 * MD2);  // 6 matrices
  float*          hy   = (float*)(ws + 4 * MD2 + 6 * W1);
  float*          ln1f = (float*)(ws + 4 * MD2 + 6 * W1 + MD4);
  // buffer reuse after their consumers are done:
  unsigned short* ln1b = Qp;   // attn consumed Qp before ln1 is produced
  unsigned short* f1   = Kp;

  // weight transposes: [K][N] -> [N][K] bf16
  dim3 tg(16, 16);
  transpose_cast_kernel<<<tg, 256, 0, stream>>>(Wq, Wt + 0 * 512 * 512);
  transpose_cast_kernel<<<tg, 256, 0, stream>>>(Wk, Wt + 1 * 512 * 512);
  transpose_cast_kernel<<<tg, 256, 0, stream>>>(Wv, Wt + 2 * 512 * 512);
  transpose_cast_kernel<<<tg, 256, 0, stream>>>(Wo, Wt + 3 * 512 * 512);
  transpose_cast_kernel<<<tg, 256, 0, stream>>>(Wh, Wt + 4 * 512 * 512);
  transpose_cast_kernel<<<tg, 256, 0, stream>>>(W2, Wt + 5 * 512 * 512);

  dim3 gg(MTOT / 64, 512 / 128);  // 128 x 4 = 512 blocks
  // projections (fused f32->bf16 cast in A staging)
  gemm_kernel<EPI_BF16, 1><<<gg, 256, 0, stream>>>(q_in, Wt + 0 * 512 * 512, bq, nullptr, Qp);
  gemm_kernel<EPI_BF16, 1><<<gg, 256, 0, stream>>>(k_in, Wt + 1 * 512 * 512, bk, nullptr, Kp);
  gemm_kernel<EPI_VT, 1><<<gg, 256, 0, stream>>>(v_in, Wt + 2 * 512 * 512, bv, nullptr, Vt);
  // attention
  dim3 ag(TSEQ / 64, BATCH * NH);
  attn_kernel<<<ag, 256, 0, stream>>>(Qp, Kp, Vt, attn);
  // h = attn @ Wo + bo + q
  gemm_kernel<EPI_F32RES, 0><<<gg, 256, 0, stream>>>(attn, Wt + 3 * 512 * 512, bo, q_in, hy);
  // LN1 -> bf16 + f32
  ln_kernel<1><<<MTOT / 4, 256, 0, stream>>>(hy, g1, be1, ln1f, ln1b);
  // f1 = leaky(ln1 @ Wh + bh)
  gemm_kernel<EPI_LRELU, 0><<<gg, 256, 0, stream>>>(ln1b, Wt + 4 * 512 * 512, bh, nullptr, f1);
  // y = f1 @ W2 + b2 + ln1
  gemm_kernel<EPI_F32RES, 0><<<gg, 256, 0, stream>>>(f1, Wt + 5 * 512 * 512, b2, ln1f, hy);
  // LN2 -> out (fp32)
  ln_kernel<0><<<MTOT / 4, 256, 0, stream>>>(hy, g2, be2, (float*)d_out, nullptr);
}

// Round 3
// 287.414 us; speedup vs baseline: 1.2853x; 1.1518x over previous
//
#include <hip/hip_runtime.h>

#define DIN   512
#define TSEQ  2048
#define BATCH 4
#define NH    8
#define DHEAD 64
#define MTOT  8192   // BATCH*TSEQ

typedef __attribute__((ext_vector_type(8))) __bf16 bf16x8;
typedef __attribute__((ext_vector_type(8))) short  s16x8;
typedef __attribute__((ext_vector_type(4))) float  f32x4;

__device__ __forceinline__ unsigned short f2b(float f) {
  union { float f; unsigned int u; } c; c.f = f;
  unsigned int r = (c.u + 0x7fffu + ((c.u >> 16) & 1u)) >> 16;
  return (unsigned short)r;
}

__device__ __forceinline__ unsigned int pkbf(float a, float b) {
  union { __bf16 h[2]; unsigned int u; } c;
  c.h[0] = (__bf16)a; c.h[1] = (__bf16)b; return c.u;
}

__device__ __forceinline__ f32x4 mfma16(bf16x8 a, bf16x8 b, f32x4 c) {
  return __builtin_amdgcn_mfma_f32_16x16x32_bf16(a, b, c, 0, 0, 0);
}

// async global->LDS, 16B per lane. lds base must be wave-uniform; HW writes
// lane i's 16B at base + i*16. Generic->AS3 via uintptr truncation (LDS
// aperture keeps offset in low 32 bits).
__device__ __forceinline__ void gload16(const void* gsrc, void* ldsbase) {
  __builtin_amdgcn_global_load_lds(
      (const __attribute__((address_space(1))) unsigned int*)gsrc,
      (__attribute__((address_space(3))) unsigned int*)(unsigned int)(unsigned long long)ldsbase,
      16, 0, 0);
}

#define VMCNT0_BARRIER() do { \
    asm volatile("s_waitcnt vmcnt(0)" ::: "memory"); \
    __builtin_amdgcn_s_barrier(); } while (0)

// ---------------------------------------------------------------- cast f32->bf16 (3 tensors)
__global__ __launch_bounds__(256) void cast3_kernel(const float* __restrict__ q,
                                                    const float* __restrict__ k,
                                                    const float* __restrict__ v,
                                                    unsigned short* __restrict__ oq,
                                                    unsigned short* __restrict__ ok,
                                                    unsigned short* __restrict__ ov) {
  const float* in = blockIdx.y == 0 ? q : blockIdx.y == 1 ? k : v;
  unsigned short* out = blockIdx.y == 0 ? oq : blockIdx.y == 1 ? ok : ov;
  int i = (blockIdx.x * 256 + threadIdx.x) * 8;
  float4 a = *(const float4*)(in + i);
  float4 b = *(const float4*)(in + i + 4);
  ushort4 u0, u1;
  u0.x = f2b(a.x); u0.y = f2b(a.y); u0.z = f2b(a.z); u0.w = f2b(a.w);
  u1.x = f2b(b.x); u1.y = f2b(b.y); u1.z = f2b(b.z); u1.w = f2b(b.w);
  *(ushort4*)(out + i) = u0;
  *(ushort4*)(out + i + 4) = u1;
}

// ---------------------------- 6x W [K][N] f32 -> Wt [N][K] bf16 (one launch)
__global__ __launch_bounds__(256) void transpose6_kernel(const float* __restrict__ w0,
                                                         const float* __restrict__ w1,
                                                         const float* __restrict__ w2,
                                                         const float* __restrict__ w3,
                                                         const float* __restrict__ w4,
                                                         const float* __restrict__ w5,
                                                         unsigned short* __restrict__ Wt) {
  const float* W;
  switch (blockIdx.z) {
    case 0: W = w0; break; case 1: W = w1; break; case 2: W = w2; break;
    case 3: W = w3; break; case 4: W = w4; break; default: W = w5; break;
  }
  unsigned short* dst = Wt + (size_t)blockIdx.z * 512 * 512;
  __shared__ float tile[32][33];
  int bx = blockIdx.x * 32, by = blockIdx.y * 32;
  int tx = threadIdx.x & 31, ty = threadIdx.x >> 5;
  #pragma unroll
  for (int yy = ty; yy < 32; yy += 8)
    tile[yy][tx] = W[(size_t)(by + yy) * DIN + bx + tx];
  __syncthreads();
  #pragma unroll
  for (int yy = ty; yy < 32; yy += 8)
    dst[(size_t)(bx + yy) * DIN + by + tx] = f2b(tile[tx][yy]);
}

// ---------------------------------------------------------------- GEMM core (m97 structure)
// 128x128 tile, BK=32, 4 waves (2x2), acc 4x4, global_load_lds + 2-phase dbuf.
__device__ __forceinline__ void gemm_core(const unsigned short* __restrict__ A,
                                          const unsigned short* __restrict__ Bt,
                                          int m0, int n0,
                                          unsigned short (*Als)[128 * 32],
                                          unsigned short (*Bls)[128 * 32],
                                          f32x4 (*acc)[4]) {
  const int tid = threadIdx.x, lane = tid & 63, w = tid >> 6;
  const int wr = w >> 1, wc = w & 1;
  const int l = lane & 15, g = lane >> 4;
  const int srow = lane >> 2;        // 0..15 within a 1KB instruction
  const int sce  = (lane & 3) * 8;   // element col within 32-elem row

  // per wave: stage 2 A-instrs + 2 B-instrs per K-step
  #define STAGE(buf, k0) do { \
      _Pragma("unroll") \
      for (int i_ = 0; i_ < 2; ++i_) { \
        int ii_ = w * 2 + i_; \
        int row_ = ii_ * 16 + srow; \
        gload16(A  + (size_t)(m0 + row_) * 512 + (k0) + sce, &Als[buf][ii_ * 512]); \
        gload16(Bt + (size_t)(n0 + row_) * 512 + (k0) + sce, &Bls[buf][ii_ * 512]); \
      } } while (0)

  STAGE(0, 0);
  VMCNT0_BARRIER();
  for (int t = 0; t < 16; ++t) {
    int cur = t & 1;
    if (t < 15) STAGE(cur ^ 1, (t + 1) * 32);
    bf16x8 af[4], bf[4];
    #pragma unroll
    for (int m = 0; m < 4; ++m)
      af[m] = *(const bf16x8*)(&Als[cur][(wr * 64 + m * 16 + l) * 32 + g * 8]);
    #pragma unroll
    for (int n = 0; n < 4; ++n)
      bf[n] = *(const bf16x8*)(&Bls[cur][(wc * 64 + n * 16 + l) * 32 + g * 8]);
    #pragma unroll
    for (int m = 0; m < 4; ++m)
      #pragma unroll
      for (int n = 0; n < 4; ++n)
        acc[m][n] = mfma16(af[m], bf[n], acc[m][n]);
    VMCNT0_BARRIER();
  }
  #undef STAGE
}

enum { EPI_BF16 = 0, EPI_F32RES = 2, EPI_LRELU = 3 };

template <int EPI>
__global__ __launch_bounds__(256) void gemm_kernel(const unsigned short* __restrict__ A,
                                                   const unsigned short* __restrict__ Bt,
                                                   const float* __restrict__ bias,
                                                   const float* __restrict__ res,
                                                   void* __restrict__ out) {
  __shared__ unsigned short Als[2][128 * 32];
  __shared__ unsigned short Bls[2][128 * 32];
  const int lane = threadIdx.x & 63, w = threadIdx.x >> 6;
  const int wr = w >> 1, wc = w & 1;
  const int l = lane & 15, g = lane >> 4;
  const int m0 = blockIdx.x * 128, n0 = blockIdx.y * 128;
  f32x4 acc[4][4] = {};
  gemm_core(A, Bt, m0, n0, Als, Bls, acc);

  #pragma unroll
  for (int m = 0; m < 4; ++m) {
    int grb = m0 + wr * 64 + m * 16 + g * 4;
    #pragma unroll
    for (int n = 0; n < 4; ++n) {
      int gc = n0 + wc * 64 + n * 16 + l;
      float bv = bias[gc];
      #pragma unroll
      for (int r = 0; r < 4; ++r) {
        int gr = grb + r;
        float v = acc[m][n][r] + bv;
        if (EPI == EPI_F32RES) {
          ((float*)out)[(size_t)gr * 512 + gc] = v + res[(size_t)gr * 512 + gc];
        } else if (EPI == EPI_BF16) {
          ((unsigned short*)out)[(size_t)gr * 512 + gc] = f2b(v);
        } else {  // EPI_LRELU
          v = v > 0.f ? v : 0.01f * v;
          ((unsigned short*)out)[(size_t)gr * 512 + gc] = f2b(v);
        }
      }
    }
  }
}

// QKV fused (grid.z selects which projection); z=2 writes transposed V.
__global__ __launch_bounds__(256) void gemm_qkv_kernel(const unsigned short* __restrict__ qb,
                                                       const unsigned short* __restrict__ kb,
                                                       const unsigned short* __restrict__ vb,
                                                       const unsigned short* __restrict__ Wt,
                                                       const float* __restrict__ bq,
                                                       const float* __restrict__ bk,
                                                       const float* __restrict__ bv,
                                                       unsigned short* __restrict__ Qp,
                                                       unsigned short* __restrict__ Kp,
                                                       unsigned short* __restrict__ Vt) {
  __shared__ unsigned short Als[2][128 * 32];
  __shared__ unsigned short Bls[2][128 * 32];
  const int z = blockIdx.z;
  const unsigned short* A = z == 0 ? qb : z == 1 ? kb : vb;
  const unsigned short* B = Wt + (size_t)z * 512 * 512;
  const float* bias = z == 0 ? bq : z == 1 ? bk : bv;
  const int lane = threadIdx.x & 63, w = threadIdx.x >> 6;
  const int wr = w >> 1, wc = w & 1;
  const int l = lane & 15, g = lane >> 4;
  const int m0 = blockIdx.x * 128, n0 = blockIdx.y * 128;
  f32x4 acc[4][4] = {};
  gemm_core(A, B, m0, n0, Als, Bls, acc);

  #pragma unroll
  for (int m = 0; m < 4; ++m) {
    int grb = m0 + wr * 64 + m * 16 + g * 4;
    #pragma unroll
    for (int n = 0; n < 4; ++n) {
      int gc = n0 + wc * 64 + n * 16 + l;
      float bvl = bias[gc];
      #pragma unroll
      for (int r = 0; r < 4; ++r) {
        int gr = grb + r;
        float v = acc[m][n][r] + bvl;
        if (z == 0) {
          Qp[(size_t)gr * 512 + gc] = f2b(v);
        } else if (z == 1) {
          Kp[(size_t)gr * 512 + gc] = f2b(v);
        } else {  // transposed: Vt[(b*512+gc)][t]
          int b = gr >> 11, t = gr & 2047;
          Vt[((size_t)(b * 512 + gc) << 11) + t] = f2b(v);
        }
      }
    }
  }
}

// ---------------------------------------------------------------- flash attention
// Triangle-paired blocks: block j handles q-tiles {31-j, j} (33 steps uniform).
// K/V staged via global_load_lds into XOR-swizzled [rows][64] LDS, 2-phase dbuf.
__global__ __launch_bounds__(256) void attn_kernel(const unsigned short* __restrict__ Q,
                                                   const unsigned short* __restrict__ K,
                                                   const unsigned short* __restrict__ Vt,
                                                   unsigned short* __restrict__ O) {
  __shared__ unsigned short Kls[2][64 * 64];
  __shared__ unsigned short Vls[2][64 * 64];
  __shared__ unsigned short Pls[4][16 * 64];
  const int tid = threadIdx.x, lane = tid & 63, w = tid >> 6;
  const int l = lane & 15, g = lane >> 4;
  const int j = blockIdx.x;            // 0..15
  const int bh = blockIdx.y;
  const int b = bh >> 3, h = bh & 7;
  const int sx = (l & 7) * 8;          // read-side swizzle (elements)
  const int n1 = 32 - j;               // steps in tile1

  // staging geometry: instr ii covers rows ii*8..ii*8+7; lane -> (r8, swizzled col)
  const int r8 = lane >> 3;
  const int sce = ((lane & 7) ^ r8) * 8;  // inverse-swizzled source col (elements)

  #define STAGEKV(buf, kv0) do { \
      _Pragma("unroll") \
      for (int i_ = 0; i_ < 2; ++i_) { \
        int ii_ = w * 2 + i_; \
        int row_ = ii_ * 8 + r8; \
        gload16(K  + (size_t)(b * 2048 + (kv0) + row_) * 512 + h * 64 + sce, &Kls[buf][ii_ * 512]); \
        gload16(Vt + (size_t)(b * 512 + h * 64 + row_) * 2048 + (kv0) + sce, &Vls[buf][ii_ * 512]); \
      } } while (0)

  int tile = 31 - j;
  int q0 = tile * 64 + w * 16;
  bf16x8 qf[2];
  #pragma unroll
  for (int kf = 0; kf < 2; ++kf)
    qf[kf] = *(const bf16x8*)(Q + (size_t)(b * 2048 + q0 + l) * 512 + h * 64 + kf * 32 + g * 8);

  float mrun = -1e30f, lrun = 0.f;
  f32x4 o[4] = {};

  STAGEKV(0, 0);
  VMCNT0_BARRIER();

  for (int s = 0; s <= 32; ++s) {
    int cur = s & 1;
    int kb = s < n1 ? s : s - n1;
    int kv0 = kb * 64;
    if (s < 32) {
      int kbn = (s + 1) < n1 ? (s + 1) : (s + 1) - n1;
      STAGEKV(cur ^ 1, kbn * 64);
    }

    // S^T: lane holds S[q=q0+l][kv = kv0 + t*16 + g*4 + r]
    f32x4 st[4];
    #pragma unroll
    for (int t = 0; t < 4; ++t) {
      st[t] = f32x4{0.f, 0.f, 0.f, 0.f};
      #pragma unroll
      for (int kf = 0; kf < 2; ++kf) {
        bf16x8 kfr = *(const bf16x8*)(&Kls[cur][(t * 16 + l) * 64 + ((kf * 32 + g * 8) ^ sx)]);
        st[t] = mfma16(kfr, qf[kf], st[t]);
      }
    }
    const bool diag = (kb == tile);
    const int qrow = q0 + l;
    #pragma unroll
    for (int t = 0; t < 4; ++t)
      #pragma unroll
      for (int r = 0; r < 4; ++r) {
        float v = st[t][r] * 0.125f;
        if (diag && (kv0 + t * 16 + g * 4 + r > qrow)) v = -1e30f;
        st[t][r] = v;
      }

    float mx = fmaxf(fmaxf(fmaxf(st[0][0], st[0][1]), fmaxf(st[0][2], st[0][3])),
                     fmaxf(fmaxf(st[1][0], st[1][1]), fmaxf(st[1][2], st[1][3])));
    mx = fmaxf(mx, fmaxf(fmaxf(fmaxf(st[2][0], st[2][1]), fmaxf(st[2][2], st[2][3])),
                         fmaxf(fmaxf(st[3][0], st[3][1]), fmaxf(st[3][2], st[3][3]))));
    mx = fmaxf(mx, __shfl_xor(mx, 16, 64));
    mx = fmaxf(mx, __shfl_xor(mx, 32, 64));
    float nm = fmaxf(mrun, mx);
    float alpha = __expf(mrun - nm);
    mrun = nm;
    float rs = 0.f;
    #pragma unroll
    for (int t = 0; t < 4; ++t)
      #pragma unroll
      for (int r = 0; r < 4; ++r) {
        float p = __expf(st[t][r] - nm);
        st[t][r] = p;
        rs += p;
      }
    rs += __shfl_xor(rs, 16, 64);
    rs += __shfl_xor(rs, 32, 64);
    lrun = lrun * alpha + rs;

    #pragma unroll
    for (int r = 0; r < 4; ++r) {
      float ar = __shfl(alpha, g * 4 + r, 64);
      #pragma unroll
      for (int n = 0; n < 4; ++n) o[n][r] *= ar;
    }

    // P pack -> swizzled LDS [16][64], then PV
    #pragma unroll
    for (int t = 0; t < 4; ++t) {
      uint2 u;
      u.x = pkbf(st[t][0], st[t][1]);
      u.y = pkbf(st[t][2], st[t][3]);
      *(uint2*)(&Pls[w][l * 64 + ((t * 16 + g * 4) ^ sx)]) = u;
    }
    #pragma unroll
    for (int kf = 0; kf < 2; ++kf) {
      bf16x8 pa = *(const bf16x8*)(&Pls[w][l * 64 + ((kf * 32 + g * 8) ^ sx)]);
      #pragma unroll
      for (int n = 0; n < 4; ++n) {
        bf16x8 vf = *(const bf16x8*)(&Vls[cur][(n * 16 + l) * 64 + ((kf * 32 + g * 8) ^ sx)]);
        o[n] = mfma16(pa, vf, o[n]);
      }
    }

    if (s == n1 - 1) {
      // finish tile1: write O, reset, load tile2's Q
      float li = 1.f / lrun;
      #pragma unroll
      for (int r = 0; r < 4; ++r) {
        float lir = __shfl(li, g * 4 + r, 64);
        #pragma unroll
        for (int n = 0; n < 4; ++n)
          O[(size_t)(b * 2048 + q0 + g * 4 + r) * 512 + h * 64 + n * 16 + l] =
              f2b(o[n][r] * lir);
      }
      tile = j;
      q0 = tile * 64 + w * 16;
      #pragma unroll
      for (int kf = 0; kf < 2; ++kf)
        qf[kf] = *(const bf16x8*)(Q + (size_t)(b * 2048 + q0 + l) * 512 + h * 64 + kf * 32 + g * 8);
      mrun = -1e30f; lrun = 0.f;
      #pragma unroll
      for (int n = 0; n < 4; ++n) o[n] = f32x4{0.f, 0.f, 0.f, 0.f};
    }
    VMCNT0_BARRIER();
  }

  float li = 1.f / lrun;
  #pragma unroll
  for (int r = 0; r < 4; ++r) {
    float lir = __shfl(li, g * 4 + r, 64);
    #pragma unroll
    for (int n = 0; n < 4; ++n)
      O[(size_t)(b * 2048 + q0 + g * 4 + r) * 512 + h * 64 + n * 16 + l] =
          f2b(o[n][r] * lir);
  }
  #undef STAGEKV
}

// ---------------------------------------------------------------- LayerNorm (wave per row)
template <int WRITE_BF16>
__global__ __launch_bounds__(256) void ln_kernel(const float* __restrict__ X,
                                                 const float* __restrict__ g,
                                                 const float* __restrict__ be,
                                                 float* __restrict__ Yf,
                                                 unsigned short* __restrict__ Yb) {
  int row = blockIdx.x * 4 + (threadIdx.x >> 6);
  int lane = threadIdx.x & 63;
  const float* x = X + (size_t)row * 512;
  float4 v0 = *(const float4*)(x + lane * 4);
  float4 v1 = *(const float4*)(x + 256 + lane * 4);
  float s = v0.x + v0.y + v0.z + v0.w + v1.x + v1.y + v1.z + v1.w;
  #pragma unroll
  for (int t = 1; t < 64; t <<= 1) s += __shfl_xor(s, t, 64);
  float mu = s * (1.f / 512.f);
  float q = 0.f;
  q += (v0.x - mu) * (v0.x - mu); q += (v0.y - mu) * (v0.y - mu);
  q += (v0.z - mu) * (v0.z - mu); q += (v0.w - mu) * (v0.w - mu);
  q += (v1.x - mu) * (v1.x - mu); q += (v1.y - mu) * (v1.y - mu);
  q += (v1.z - mu) * (v1.z - mu); q += (v1.w - mu) * (v1.w - mu);
  #pragma unroll
  for (int t = 1; t < 64; t <<= 1) q += __shfl_xor(q, t, 64);
  float rstd = rsqrtf(q * (1.f / 512.f) + 1e-5f);

  float4 g0 = *(const float4*)(g + lane * 4);
  float4 g1 = *(const float4*)(g + 256 + lane * 4);
  float4 b0 = *(const float4*)(be + lane * 4);
  float4 b1 = *(const float4*)(be + 256 + lane * 4);
  float4 y0, y1;
  y0.x = (v0.x - mu) * rstd * g0.x + b0.x; y0.y = (v0.y - mu) * rstd * g0.y + b0.y;
  y0.z = (v0.z - mu) * rstd * g0.z + b0.z; y0.w = (v0.w - mu) * rstd * g0.w + b0.w;
  y1.x = (v1.x - mu) * rstd * g1.x + b1.x; y1.y = (v1.y - mu) * rstd * g1.y + b1.y;
  y1.z = (v1.z - mu) * rstd * g1.z + b1.z; y1.w = (v1.w - mu) * rstd * g1.w + b1.w;
  if (Yf) {
    *(float4*)(Yf + (size_t)row * 512 + lane * 4) = y0;
    *(float4*)(Yf + (size_t)row * 512 + 256 + lane * 4) = y1;
  }
  if (WRITE_BF16) {
    ushort4 u0, u1;
    u0.x = f2b(y0.x); u0.y = f2b(y0.y); u0.z = f2b(y0.z); u0.w = f2b(y0.w);
    u1.x = f2b(y1.x); u1.y = f2b(y1.y); u1.z = f2b(y1.z); u1.w = f2b(y1.w);
    *(ushort4*)(Yb + (size_t)row * 512 + lane * 4) = u0;
    *(ushort4*)(Yb + (size_t)row * 512 + 256 + lane * 4) = u1;
  }
}

// ---------------------------------------------------------------- launch
extern "C" void kernel_launch(void* const* d_in, const int* in_sizes, int n_in,
                              void* d_out, int out_size, void* d_ws, size_t ws_size,
                              hipStream_t stream) {
  const float* q_in = (const float*)d_in[0];
  const float* k_in = (const float*)d_in[1];
  const float* v_in = (const float*)d_in[2];
  const float* Wq = (const float*)d_in[3];  const float* bq = (const float*)d_in[4];
  const float* Wk = (const float*)d_in[5];  const float* bk = (const float*)d_in[6];
  const float* Wv = (const float*)d_in[7];  const float* bv = (const float*)d_in[8];
  const float* Wo = (const float*)d_in[9];  const float* bo = (const float*)d_in[10];
  const float* Wh = (const float*)d_in[11]; const float* bh = (const float*)d_in[12];
  const float* W2 = (const float*)d_in[13]; const float* b2 = (const float*)d_in[14];
  const float* g1 = (const float*)d_in[15]; const float* be1 = (const float*)d_in[16];
  const float* g2 = (const float*)d_in[17]; const float* be2 = (const float*)d_in[18];

  char* ws = (char*)d_ws;
  const size_t MD2 = (size_t)MTOT * 512 * 2;   // 8 MB bf16 buffer
  const size_t W1  = (size_t)512 * 512 * 2;
  const size_t MD4 = (size_t)MTOT * 512 * 4;   // 16 MB f32 buffer
  unsigned short* qb_  = (unsigned short*)(ws);
  unsigned short* kb_  = (unsigned short*)(ws + MD2);
  unsigned short* vb_  = (unsigned short*)(ws + 2 * MD2);
  unsigned short* Qp   = (unsigned short*)(ws + 3 * MD2);
  unsigned short* Kp   = (unsigned short*)(ws + 4 * MD2);
  unsigned short* Vt   = (unsigned short*)(ws + 5 * MD2);
  unsigned short* Wt   = (unsigned short*)(ws + 6 * MD2);  // 6 matrices
  float*          hy   = (float*)(ws + 6 * MD2 + 6 * W1);
  float*          ln1f = (float*)(ws + 6 * MD2 + 6 * W1 + MD4);
  // aliases (consumers done before producers write):
  unsigned short* attn = vb_;   // vb consumed by QKV gemm before attn runs
  unsigned short* ln1b = qb_;
  unsigned short* f1   = kb_;

  cast3_kernel<<<dim3(MTOT * 512 / 2048, 3), 256, 0, stream>>>(q_in, k_in, v_in, qb_, kb_, vb_);
  transpose6_kernel<<<dim3(16, 16, 6), 256, 0, stream>>>(Wq, Wk, Wv, Wo, Wh, W2, Wt);

  // fused QKV projections (z: 0=Q,1=K,2=V-transposed)
  gemm_qkv_kernel<<<dim3(MTOT / 128, 4, 3), 256, 0, stream>>>(
      qb_, kb_, vb_, Wt, bq, bk, bv, Qp, Kp, Vt);

  // attention: triangle-paired blocks
  attn_kernel<<<dim3(16, BATCH * NH), 256, 0, stream>>>(Qp, Kp, Vt, attn);

  dim3 gg(MTOT / 128, 4);
  // h = attn @ Wo + bo + q
  gemm_kernel<EPI_F32RES><<<gg, 256, 0, stream>>>(attn, Wt + 3 * 512 * 512, bo, q_in, hy);
  ln_kernel<1><<<MTOT / 4, 256, 0, stream>>>(hy, g1, be1, ln1f, ln1b);
  // f1 = leaky(ln1 @ Wh + bh)
  gemm_kernel<EPI_LRELU><<<gg, 256, 0, stream>>>(ln1b, Wt + 4 * 512 * 512, bh, nullptr, f1);
  // y = f1 @ W2 + b2 + ln1
  gemm_kernel<EPI_F32RES><<<gg, 256, 0, stream>>>(f1, Wt + 5 * 512 * 512, b2, ln1f, hy);
  ln_kernel<0><<<MTOT / 4, 256, 0, stream>>>(hy, g2, be2, (float*)d_out, nullptr);
}

// Round 4
// 258.858 us; speedup vs baseline: 1.4271x; 1.1103x over previous
//
#include <hip/hip_runtime.h>
#include <math.h>

#define DIN   512
#define TSEQ  2048
#define BATCH 4
#define NH    8
#define DHEAD 64
#define MTOT  8192   // BATCH*TSEQ

typedef __attribute__((ext_vector_type(8))) __bf16 bf16x8;
typedef __attribute__((ext_vector_type(8))) short  s16x8;
typedef __attribute__((ext_vector_type(4))) float  f32x4;

__device__ __forceinline__ unsigned short f2b(float f) {
  union { float f; unsigned int u; } c; c.f = f;
  unsigned int r = (c.u + 0x7fffu + ((c.u >> 16) & 1u)) >> 16;
  return (unsigned short)r;
}

__device__ __forceinline__ unsigned int pkbf(float a, float b) {
  union { __bf16 h[2]; unsigned int u; } c;
  c.h[0] = (__bf16)a; c.h[1] = (__bf16)b; return c.u;
}

__device__ __forceinline__ f32x4 mfma16(bf16x8 a, bf16x8 b, f32x4 c) {
  return __builtin_amdgcn_mfma_f32_16x16x32_bf16(a, b, c, 0, 0, 0);
}

// async global->LDS, 16B per lane; LDS dest = wave-uniform base + lane*16.
__device__ __forceinline__ void gload16(const void* gsrc, void* ldsbase) {
  __builtin_amdgcn_global_load_lds(
      (const __attribute__((address_space(1))) unsigned int*)gsrc,
      (__attribute__((address_space(3))) unsigned int*)(unsigned int)(unsigned long long)ldsbase,
      16, 0, 0);
}

#define VMCNT0_BARRIER() do { \
    asm volatile("s_waitcnt vmcnt(0)" ::: "memory"); \
    __builtin_amdgcn_s_barrier(); } while (0)

// ---------------------------------------------------------------- cast f32->bf16 (3 tensors)
__global__ __launch_bounds__(256) void cast3_kernel(const float* __restrict__ q,
                                                    const float* __restrict__ k,
                                                    const float* __restrict__ v,
                                                    unsigned short* __restrict__ oq,
                                                    unsigned short* __restrict__ ok,
                                                    unsigned short* __restrict__ ov) {
  const float* in = blockIdx.y == 0 ? q : blockIdx.y == 1 ? k : v;
  unsigned short* out = blockIdx.y == 0 ? oq : blockIdx.y == 1 ? ok : ov;
  int i = (blockIdx.x * 256 + threadIdx.x) * 8;
  float4 a = *(const float4*)(in + i);
  float4 b = *(const float4*)(in + i + 4);
  ushort4 u0, u1;
  u0.x = f2b(a.x); u0.y = f2b(a.y); u0.z = f2b(a.z); u0.w = f2b(a.w);
  u1.x = f2b(b.x); u1.y = f2b(b.y); u1.z = f2b(b.z); u1.w = f2b(b.w);
  *(ushort4*)(out + i) = u0;
  *(ushort4*)(out + i + 4) = u1;
}

// ---------------------------- 6x W [K][N] f32 -> Wt [N][K] bf16 (one launch)
__global__ __launch_bounds__(256) void transpose6_kernel(const float* __restrict__ w0,
                                                         const float* __restrict__ w1,
                                                         const float* __restrict__ w2,
                                                         const float* __restrict__ w3,
                                                         const float* __restrict__ w4,
                                                         const float* __restrict__ w5,
                                                         unsigned short* __restrict__ Wt) {
  const float* W;
  switch (blockIdx.z) {
    case 0: W = w0; break; case 1: W = w1; break; case 2: W = w2; break;
    case 3: W = w3; break; case 4: W = w4; break; default: W = w5; break;
  }
  unsigned short* dst = Wt + (size_t)blockIdx.z * 512 * 512;
  __shared__ float tile[32][33];
  int bx = blockIdx.x * 32, by = blockIdx.y * 32;
  int tx = threadIdx.x & 31, ty = threadIdx.x >> 5;
  #pragma unroll
  for (int yy = ty; yy < 32; yy += 8)
    tile[yy][tx] = W[(size_t)(by + yy) * DIN + bx + tx];
  __syncthreads();
  #pragma unroll
  for (int yy = ty; yy < 32; yy += 8)
    dst[(size_t)(bx + yy) * DIN + by + tx] = f2b(tile[tx][yy]);
}

// ---------------------------------------------------------------- GEMM core
// BM=64, BN=128, BK=64; 4 waves (2x2), wave tile 32x64, acc 2x4.
// global_load_lds staging, T2 XOR-swizzle, T3 minimum 2-phase pipeline.
__device__ __forceinline__ void gemm_core(const unsigned short* __restrict__ A,
                                          const unsigned short* __restrict__ Bt,
                                          int m0, int n0,
                                          unsigned short (*Als)[64 * 64],
                                          unsigned short (*Bls)[128 * 64],
                                          f32x4 (*acc)[4]) {
  const int tid = threadIdx.x, lane = tid & 63, w = tid >> 6;
  const int wr = w >> 1, wc = w & 1;
  const int l = lane & 15, g = lane >> 4;
  const int r8 = lane >> 3;                 // row within 8-row stripe of one instr
  const int sce = ((lane & 7) ^ r8) * 8;    // inverse-swizzled source col (elems)
  const int sxr = (l & 7) * 8;              // read-side swizzle for row l (elems)

  // per wave: 2 A-instrs + 4 B-instrs per K-step (each instr = 1KB = 8 rows x 64)
  #define GSTAGE(buf, k0) do { \
      _Pragma("unroll") \
      for (int i_ = 0; i_ < 2; ++i_) { \
        int ia_ = w * 2 + i_; \
        gload16(A + (size_t)(m0 + ia_ * 8 + r8) * 512 + (k0) + sce, &Als[buf][ia_ * 512]); \
      } \
      _Pragma("unroll") \
      for (int i_ = 0; i_ < 4; ++i_) { \
        int ib_ = w * 4 + i_; \
        gload16(Bt + (size_t)(n0 + ib_ * 8 + r8) * 512 + (k0) + sce, &Bls[buf][ib_ * 512]); \
      } } while (0)

  GSTAGE(0, 0);
  VMCNT0_BARRIER();
  for (int t = 0; t < 8; ++t) {
    int cur = t & 1;
    if (t < 7) GSTAGE(cur ^ 1, (t + 1) * 64);   // issue next-tile loads FIRST
    #pragma unroll
    for (int kk = 0; kk < 2; ++kk) {
      bf16x8 af[2], bf[4];
      #pragma unroll
      for (int m = 0; m < 2; ++m)
        af[m] = *(const bf16x8*)(&Als[cur][(wr * 32 + m * 16 + l) * 64 + ((kk * 32 + g * 8) ^ sxr)]);
      #pragma unroll
      for (int n = 0; n < 4; ++n)
        bf[n] = *(const bf16x8*)(&Bls[cur][(wc * 64 + n * 16 + l) * 64 + ((kk * 32 + g * 8) ^ sxr)]);
      #pragma unroll
      for (int m = 0; m < 2; ++m)
        #pragma unroll
        for (int n = 0; n < 4; ++n)
          acc[m][n] = mfma16(af[m], bf[n], acc[m][n]);
    }
    VMCNT0_BARRIER();   // one drain+barrier per K-step
  }
  #undef GSTAGE
}

enum { EPI_BF16 = 0, EPI_F32RES = 2, EPI_LRELU = 3 };

template <int EPI>
__global__ __launch_bounds__(256) void gemm_kernel(const unsigned short* __restrict__ A,
                                                   const unsigned short* __restrict__ Bt,
                                                   const float* __restrict__ bias,
                                                   const float* __restrict__ res,
                                                   void* __restrict__ out) {
  __shared__ unsigned short Als[2][64 * 64];
  __shared__ unsigned short Bls[2][128 * 64];
  const int lane = threadIdx.x & 63, w = threadIdx.x >> 6;
  const int wr = w >> 1, wc = w & 1;
  const int l = lane & 15, g = lane >> 4;
  const int m0 = blockIdx.x * 64, n0 = blockIdx.y * 128;
  f32x4 acc[2][4] = {};
  gemm_core(A, Bt, m0, n0, Als, Bls, acc);

  #pragma unroll
  for (int m = 0; m < 2; ++m) {
    int grb = m0 + wr * 32 + m * 16 + g * 4;
    #pragma unroll
    for (int n = 0; n < 4; ++n) {
      int gc = n0 + wc * 64 + n * 16 + l;
      float bv = bias[gc];
      #pragma unroll
      for (int r = 0; r < 4; ++r) {
        int gr = grb + r;
        float v = acc[m][n][r] + bv;
        if (EPI == EPI_F32RES) {
          ((float*)out)[(size_t)gr * 512 + gc] = v + res[(size_t)gr * 512 + gc];
        } else if (EPI == EPI_BF16) {
          ((unsigned short*)out)[(size_t)gr * 512 + gc] = f2b(v);
        } else {  // EPI_LRELU
          v = v > 0.f ? v : 0.01f * v;
          ((unsigned short*)out)[(size_t)gr * 512 + gc] = f2b(v);
        }
      }
    }
  }
}

// QKV fused (grid.z selects projection); z=2 writes transposed V.
__global__ __launch_bounds__(256) void gemm_qkv_kernel(const unsigned short* __restrict__ qb,
                                                       const unsigned short* __restrict__ kb,
                                                       const unsigned short* __restrict__ vb,
                                                       const unsigned short* __restrict__ Wt,
                                                       const float* __restrict__ bq,
                                                       const float* __restrict__ bk,
                                                       const float* __restrict__ bv,
                                                       unsigned short* __restrict__ Qp,
                                                       unsigned short* __restrict__ Kp,
                                                       unsigned short* __restrict__ Vt) {
  __shared__ unsigned short Als[2][64 * 64];
  __shared__ unsigned short Bls[2][128 * 64];
  const int z = blockIdx.z;
  const unsigned short* A = z == 0 ? qb : z == 1 ? kb : vb;
  const unsigned short* B = Wt + (size_t)z * 512 * 512;
  const float* bias = z == 0 ? bq : z == 1 ? bk : bv;
  const int lane = threadIdx.x & 63, w = threadIdx.x >> 6;
  const int wr = w >> 1, wc = w & 1;
  const int l = lane & 15, g = lane >> 4;
  const int m0 = blockIdx.x * 64, n0 = blockIdx.y * 128;
  f32x4 acc[2][4] = {};
  gemm_core(A, B, m0, n0, Als, Bls, acc);

  #pragma unroll
  for (int m = 0; m < 2; ++m) {
    int grb = m0 + wr * 32 + m * 16 + g * 4;
    #pragma unroll
    for (int n = 0; n < 4; ++n) {
      int gc = n0 + wc * 64 + n * 16 + l;
      float bvl = bias[gc];
      #pragma unroll
      for (int r = 0; r < 4; ++r) {
        int gr = grb + r;
        float v = acc[m][n][r] + bvl;
        if (z == 0) {
          Qp[(size_t)gr * 512 + gc] = f2b(v);
        } else if (z == 1) {
          Kp[(size_t)gr * 512 + gc] = f2b(v);
        } else {  // transposed: Vt[(b*512+gc)][t]
          int b = gr >> 11, t = gr & 2047;
          Vt[((size_t)(b * 512 + gc) << 11) + t] = f2b(v);
        }
      }
    }
  }
}

// ---------------------------------------------------------------- flash attention
// Triangle-paired blocks: block j handles q-tiles {31-j, j} (33 steps uniform).
// Swapped QK^T; K/V via global_load_lds into XOR-swizzled LDS, 2-phase dbuf.
// Diag masking under uniform branch; T13 defer-rescale; exp2-based softmax.
__global__ __launch_bounds__(256) void attn_kernel(const unsigned short* __restrict__ Q,
                                                   const unsigned short* __restrict__ K,
                                                   const unsigned short* __restrict__ Vt,
                                                   unsigned short* __restrict__ O) {
  __shared__ unsigned short Kls[2][64 * 64];
  __shared__ unsigned short Vls[2][64 * 64];
  __shared__ unsigned short Pls[4][16 * 64];
  const int tid = threadIdx.x, lane = tid & 63, w = tid >> 6;
  const int l = lane & 15, g = lane >> 4;
  const int j = blockIdx.x;            // 0..15
  const int bh = blockIdx.y;
  const int b = bh >> 3, h = bh & 7;
  const int sx = (l & 7) * 8;          // read-side swizzle (elems)
  const int n1 = 32 - j;               // steps in tile1
  const float SC2 = 0.125f * 1.44269504088896340736f;  // 1/sqrt(dh) * log2(e)
  const float THR = 64.f;              // raw-score defer threshold (= e^8 bound)

  const int r8 = lane >> 3;
  const int sce = ((lane & 7) ^ r8) * 8;  // inverse-swizzled source col (elems)

  #define STAGEKV(buf, kv0) do { \
      _Pragma("unroll") \
      for (int i_ = 0; i_ < 2; ++i_) { \
        int ii_ = w * 2 + i_; \
        int row_ = ii_ * 8 + r8; \
        gload16(K  + (size_t)(b * 2048 + (kv0) + row_) * 512 + h * 64 + sce, &Kls[buf][ii_ * 512]); \
        gload16(Vt + (size_t)(b * 512 + h * 64 + row_) * 2048 + (kv0) + sce, &Vls[buf][ii_ * 512]); \
      } } while (0)

  int tile = 31 - j;
  int q0 = tile * 64 + w * 16;
  bf16x8 qf[2];
  #pragma unroll
  for (int kf = 0; kf < 2; ++kf)
    qf[kf] = *(const bf16x8*)(Q + (size_t)(b * 2048 + q0 + l) * 512 + h * 64 + kf * 32 + g * 8);

  float mrun = -1e30f, lrun = 0.f;
  f32x4 o[4] = {};

  STAGEKV(0, 0);
  VMCNT0_BARRIER();

  for (int s = 0; s <= 32; ++s) {
    int cur = s & 1;
    int kb = s < n1 ? s : s - n1;
    int kv0 = kb * 64;
    if (s < 32) {
      int kbn = (s + 1) < n1 ? (s + 1) : (s + 1) - n1;
      STAGEKV(cur ^ 1, kbn * 64);
    }

    // S^T (raw scores): lane holds S[q=q0+l][kv = kv0 + t*16 + g*4 + r]
    f32x4 st[4];
    #pragma unroll
    for (int t = 0; t < 4; ++t) {
      st[t] = f32x4{0.f, 0.f, 0.f, 0.f};
      #pragma unroll
      for (int kf = 0; kf < 2; ++kf) {
        bf16x8 kfr = *(const bf16x8*)(&Kls[cur][(t * 16 + l) * 64 + ((kf * 32 + g * 8) ^ sx)]);
        st[t] = mfma16(kfr, qf[kf], st[t]);
      }
    }
    if (kb == tile) {   // uniform branch: only diagonal steps mask
      const int qrow = q0 + l;
      #pragma unroll
      for (int t = 0; t < 4; ++t)
        #pragma unroll
        for (int r = 0; r < 4; ++r)
          if (kv0 + t * 16 + g * 4 + r > qrow) st[t][r] = -1e30f;
    }

    // row max (raw units)
    float mx = fmaxf(fmaxf(fmaxf(st[0][0], st[0][1]), fmaxf(st[0][2], st[0][3])),
                     fmaxf(fmaxf(st[1][0], st[1][1]), fmaxf(st[1][2], st[1][3])));
    mx = fmaxf(mx, fmaxf(fmaxf(fmaxf(st[2][0], st[2][1]), fmaxf(st[2][2], st[2][3])),
                         fmaxf(fmaxf(st[3][0], st[3][1]), fmaxf(st[3][2], st[3][3]))));
    mx = fmaxf(mx, __shfl_xor(mx, 16, 64));
    mx = fmaxf(mx, __shfl_xor(mx, 32, 64));

    // T13 defer-rescale: only rescale when max grows past THR
    if (!__all(mx <= mrun + THR)) {
      float nm = fmaxf(mrun, mx);
      float alpha = exp2f((mrun - nm) * SC2);
      mrun = nm;
      lrun *= alpha;
      #pragma unroll
      for (int r = 0; r < 4; ++r) {
        float ar = __shfl(alpha, g * 4 + r, 64);
        #pragma unroll
        for (int n = 0; n < 4; ++n) o[n][r] *= ar;
      }
    }

    float mS = mrun * SC2;
    float rs = 0.f;
    #pragma unroll
    for (int t = 0; t < 4; ++t)
      #pragma unroll
      for (int r = 0; r < 4; ++r) {
        float p = exp2f(fmaf(st[t][r], SC2, -mS));
        st[t][r] = p;
        rs += p;
      }
    rs += __shfl_xor(rs, 16, 64);
    rs += __shfl_xor(rs, 32, 64);
    lrun += rs;

    // P pack -> swizzled LDS [16][64], then PV
    #pragma unroll
    for (int t = 0; t < 4; ++t) {
      uint2 u;
      u.x = pkbf(st[t][0], st[t][1]);
      u.y = pkbf(st[t][2], st[t][3]);
      *(uint2*)(&Pls[w][l * 64 + ((t * 16 + g * 4) ^ sx)]) = u;
    }
    #pragma unroll
    for (int kf = 0; kf < 2; ++kf) {
      bf16x8 pa = *(const bf16x8*)(&Pls[w][l * 64 + ((kf * 32 + g * 8) ^ sx)]);
      #pragma unroll
      for (int n = 0; n < 4; ++n) {
        bf16x8 vf = *(const bf16x8*)(&Vls[cur][(n * 16 + l) * 64 + ((kf * 32 + g * 8) ^ sx)]);
        o[n] = mfma16(pa, vf, o[n]);
      }
    }

    if (s == n1 - 1) {
      // finish tile1: write O, reset, load tile2's Q
      float li = 1.f / lrun;
      #pragma unroll
      for (int r = 0; r < 4; ++r) {
        float lir = __shfl(li, g * 4 + r, 64);
        #pragma unroll
        for (int n = 0; n < 4; ++n)
          O[(size_t)(b * 2048 + q0 + g * 4 + r) * 512 + h * 64 + n * 16 + l] =
              f2b(o[n][r] * lir);
      }
      tile = j;
      q0 = tile * 64 + w * 16;
      #pragma unroll
      for (int kf = 0; kf < 2; ++kf)
        qf[kf] = *(const bf16x8*)(Q + (size_t)(b * 2048 + q0 + l) * 512 + h * 64 + kf * 32 + g * 8);
      mrun = -1e30f; lrun = 0.f;
      #pragma unroll
      for (int n = 0; n < 4; ++n) o[n] = f32x4{0.f, 0.f, 0.f, 0.f};
    }
    VMCNT0_BARRIER();
  }

  float li = 1.f / lrun;
  #pragma unroll
  for (int r = 0; r < 4; ++r) {
    float lir = __shfl(li, g * 4 + r, 64);
    #pragma unroll
    for (int n = 0; n < 4; ++n)
      O[(size_t)(b * 2048 + q0 + g * 4 + r) * 512 + h * 64 + n * 16 + l] =
          f2b(o[n][r] * lir);
  }
  #undef STAGEKV
}

// ---------------------------------------------------------------- LayerNorm (wave per row)
template <int WRITE_BF16>
__global__ __launch_bounds__(256) void ln_kernel(const float* __restrict__ X,
                                                 const float* __restrict__ g,
                                                 const float* __restrict__ be,
                                                 float* __restrict__ Yf,
                                                 unsigned short* __restrict__ Yb) {
  int row = blockIdx.x * 4 + (threadIdx.x >> 6);
  int lane = threadIdx.x & 63;
  const float* x = X + (size_t)row * 512;
  float4 v0 = *(const float4*)(x + lane * 4);
  float4 v1 = *(const float4*)(x + 256 + lane * 4);
  float s = v0.x + v0.y + v0.z + v0.w + v1.x + v1.y + v1.z + v1.w;
  #pragma unroll
  for (int t = 1; t < 64; t <<= 1) s += __shfl_xor(s, t, 64);
  float mu = s * (1.f / 512.f);
  float q = 0.f;
  q += (v0.x - mu) * (v0.x - mu); q += (v0.y - mu) * (v0.y - mu);
  q += (v0.z - mu) * (v0.z - mu); q += (v0.w - mu) * (v0.w - mu);
  q += (v1.x - mu) * (v1.x - mu); q += (v1.y - mu) * (v1.y - mu);
  q += (v1.z - mu) * (v1.z - mu); q += (v1.w - mu) * (v1.w - mu);
  #pragma unroll
  for (int t = 1; t < 64; t <<= 1) q += __shfl_xor(q, t, 64);
  float rstd = rsqrtf(q * (1.f / 512.f) + 1e-5f);

  float4 g0 = *(const float4*)(g + lane * 4);
  float4 g1 = *(const float4*)(g + 256 + lane * 4);
  float4 b0 = *(const float4*)(be + lane * 4);
  float4 b1 = *(const float4*)(be + 256 + lane * 4);
  float4 y0, y1;
  y0.x = (v0.x - mu) * rstd * g0.x + b0.x; y0.y = (v0.y - mu) * rstd * g0.y + b0.y;
  y0.z = (v0.z - mu) * rstd * g0.z + b0.z; y0.w = (v0.w - mu) * rstd * g0.w + b0.w;
  y1.x = (v1.x - mu) * rstd * g1.x + b1.x; y1.y = (v1.y - mu) * rstd * g1.y + b1.y;
  y1.z = (v1.z - mu) * rstd * g1.z + b1.z; y1.w = (v1.w - mu) * rstd * g1.w + b1.w;
  if (Yf) {
    *(float4*)(Yf + (size_t)row * 512 + lane * 4) = y0;
    *(float4*)(Yf + (size_t)row * 512 + 256 + lane * 4) = y1;
  }
  if (WRITE_BF16) {
    ushort4 u0, u1;
    u0.x = f2b(y0.x); u0.y = f2b(y0.y); u0.z = f2b(y0.z); u0.w = f2b(y0.w);
    u1.x = f2b(y1.x); u1.y = f2b(y1.y); u1.z = f2b(y1.z); u1.w = f2b(y1.w);
    *(ushort4*)(Yb + (size_t)row * 512 + lane * 4) = u0;
    *(ushort4*)(Yb + (size_t)row * 512 + 256 + lane * 4) = u1;
  }
}

// ---------------------------------------------------------------- launch
extern "C" void kernel_launch(void* const* d_in, const int* in_sizes, int n_in,
                              void* d_out, int out_size, void* d_ws, size_t ws_size,
                              hipStream_t stream) {
  const float* q_in = (const float*)d_in[0];
  const float* k_in = (const float*)d_in[1];
  const float* v_in = (const float*)d_in[2];
  const float* Wq = (const float*)d_in[3];  const float* bq = (const float*)d_in[4];
  const float* Wk = (const float*)d_in[5];  const float* bk = (const float*)d_in[6];
  const float* Wv = (const float*)d_in[7];  const float* bv = (const float*)d_in[8];
  const float* Wo = (const float*)d_in[9];  const float* bo = (const float*)d_in[10];
  const float* Wh = (const float*)d_in[11]; const float* bh = (const float*)d_in[12];
  const float* W2 = (const float*)d_in[13]; const float* b2 = (const float*)d_in[14];
  const float* g1 = (const float*)d_in[15]; const float* be1 = (const float*)d_in[16];
  const float* g2 = (const float*)d_in[17]; const float* be2 = (const float*)d_in[18];

  char* ws = (char*)d_ws;
  const size_t MD2 = (size_t)MTOT * 512 * 2;   // 8 MB bf16 buffer
  const size_t W1  = (size_t)512 * 512 * 2;
  const size_t MD4 = (size_t)MTOT * 512 * 4;   // 16 MB f32 buffer
  unsigned short* qb_  = (unsigned short*)(ws);
  unsigned short* kb_  = (unsigned short*)(ws + MD2);
  unsigned short* vb_  = (unsigned short*)(ws + 2 * MD2);
  unsigned short* Qp   = (unsigned short*)(ws + 3 * MD2);
  unsigned short* Kp   = (unsigned short*)(ws + 4 * MD2);
  unsigned short* Vt   = (unsigned short*)(ws + 5 * MD2);
  unsigned short* Wt   = (unsigned short*)(ws + 6 * MD2);  // 6 matrices
  float*          hy   = (float*)(ws + 6 * MD2 + 6 * W1);
  float*          ln1f = (float*)(ws + 6 * MD2 + 6 * W1 + MD4);
  // aliases (consumers done before producers write):
  unsigned short* attn = vb_;   // vb consumed by QKV gemm before attn runs
  unsigned short* ln1b = qb_;
  unsigned short* f1   = kb_;

  cast3_kernel<<<dim3(MTOT * 512 / 2048, 3), 256, 0, stream>>>(q_in, k_in, v_in, qb_, kb_, vb_);
  transpose6_kernel<<<dim3(16, 16, 6), 256, 0, stream>>>(Wq, Wk, Wv, Wo, Wh, W2, Wt);

  // fused QKV projections (z: 0=Q,1=K,2=V-transposed)
  gemm_qkv_kernel<<<dim3(MTOT / 64, 4, 3), 256, 0, stream>>>(
      qb_, kb_, vb_, Wt, bq, bk, bv, Qp, Kp, Vt);

  // attention: triangle-paired blocks
  attn_kernel<<<dim3(16, BATCH * NH), 256, 0, stream>>>(Qp, Kp, Vt, attn);

  dim3 gg(MTOT / 64, 4);
  // h = attn @ Wo + bo + q
  gemm_kernel<EPI_F32RES><<<gg, 256, 0, stream>>>(attn, Wt + 3 * 512 * 512, bo, q_in, hy);
  ln_kernel<1><<<MTOT / 4, 256, 0, stream>>>(hy, g1, be1, ln1f, ln1b);
  // f1 = leaky(ln1 @ Wh + bh)
  gemm_kernel<EPI_LRELU><<<gg, 256, 0, stream>>>(ln1b, Wt + 4 * 512 * 512, bh, nullptr, f1);
  // y = f1 @ W2 + b2 + ln1
  gemm_kernel<EPI_F32RES><<<gg, 256, 0, stream>>>(f1, Wt + 5 * 512 * 512, b2, ln1f, hy);
  ln_kernel<0><<<MTOT / 4, 256, 0, stream>>>(hy, g2, be2, (float*)d_out, nullptr);
}

// Round 5
// 256.110 us; speedup vs baseline: 1.4424x; 1.0107x over previous
//
#include <hip/hip_runtime.h>
#include <math.h>

#define DIN   512
#define TSEQ  2048
#define BATCH 4
#define NH    8
#define DHEAD 64
#define MTOT  8192   // BATCH*TSEQ

typedef __attribute__((ext_vector_type(8))) __bf16 bf16x8;
typedef __attribute__((ext_vector_type(8))) short  s16x8;
typedef __attribute__((ext_vector_type(4))) float  f32x4;

__device__ __forceinline__ unsigned short f2b(float f) {
  union { float f; unsigned int u; } c; c.f = f;
  unsigned int r = (c.u + 0x7fffu + ((c.u >> 16) & 1u)) >> 16;
  return (unsigned short)r;
}

__device__ __forceinline__ unsigned int pkbf(float a, float b) {
  union { __bf16 h[2]; unsigned int u; } c;
  c.h[0] = (__bf16)a; c.h[1] = (__bf16)b; return c.u;
}

__device__ __forceinline__ f32x4 mfma16(bf16x8 a, bf16x8 b, f32x4 c) {
  return __builtin_amdgcn_mfma_f32_16x16x32_bf16(a, b, c, 0, 0, 0);
}

// async global->LDS, 16B per lane; LDS dest = wave-uniform base + lane*16.
__device__ __forceinline__ void gload16(const void* gsrc, void* ldsbase) {
  __builtin_amdgcn_global_load_lds(
      (const __attribute__((address_space(1))) unsigned int*)gsrc,
      (__attribute__((address_space(3))) unsigned int*)(unsigned int)(unsigned long long)ldsbase,
      16, 0, 0);
}

#define WAITV(N) asm volatile("s_waitcnt vmcnt(" #N ")" ::: "memory")

// ---------------------------------------------------------------- cast f32->bf16 (3 tensors)
__global__ __launch_bounds__(256) void cast3_kernel(const float* __restrict__ q,
                                                    const float* __restrict__ k,
                                                    const float* __restrict__ v,
                                                    unsigned short* __restrict__ oq,
                                                    unsigned short* __restrict__ ok,
                                                    unsigned short* __restrict__ ov) {
  const float* in = blockIdx.y == 0 ? q : blockIdx.y == 1 ? k : v;
  unsigned short* out = blockIdx.y == 0 ? oq : blockIdx.y == 1 ? ok : ov;
  int i = (blockIdx.x * 256 + threadIdx.x) * 8;
  float4 a = *(const float4*)(in + i);
  float4 b = *(const float4*)(in + i + 4);
  ushort4 u0, u1;
  u0.x = f2b(a.x); u0.y = f2b(a.y); u0.z = f2b(a.z); u0.w = f2b(a.w);
  u1.x = f2b(b.x); u1.y = f2b(b.y); u1.z = f2b(b.z); u1.w = f2b(b.w);
  *(ushort4*)(out + i) = u0;
  *(ushort4*)(out + i + 4) = u1;
}

// ---------------------------- 6x W [K][N] f32 -> Wt [N][K] bf16 (one launch)
__global__ __launch_bounds__(256) void transpose6_kernel(const float* __restrict__ w0,
                                                         const float* __restrict__ w1,
                                                         const float* __restrict__ w2,
                                                         const float* __restrict__ w3,
                                                         const float* __restrict__ w4,
                                                         const float* __restrict__ w5,
                                                         unsigned short* __restrict__ Wt) {
  const float* W;
  switch (blockIdx.z) {
    case 0: W = w0; break; case 1: W = w1; break; case 2: W = w2; break;
    case 3: W = w3; break; case 4: W = w4; break; default: W = w5; break;
  }
  unsigned short* dst = Wt + (size_t)blockIdx.z * 512 * 512;
  __shared__ float tile[32][33];
  int bx = blockIdx.x * 32, by = blockIdx.y * 32;
  int tx = threadIdx.x & 31, ty = threadIdx.x >> 5;
  #pragma unroll
  for (int yy = ty; yy < 32; yy += 8)
    tile[yy][tx] = W[(size_t)(by + yy) * DIN + bx + tx];
  __syncthreads();
  #pragma unroll
  for (int yy = ty; yy < 32; yy += 8)
    dst[(size_t)(bx + yy) * DIN + by + tx] = f2b(tile[tx][yy]);
}

// ---------------------------------------------------------------- GEMM core
// BM=64, BN=128, BK=64, 8 K-steps; 4 waves (2x2); 3-buf LDS, depth-2 prefetch,
// counted vmcnt(6) waits (T4), one barrier per step, XOR-swizzled LDS (T2).
__device__ __forceinline__ void gemm_core(const unsigned short* __restrict__ A,
                                          const unsigned short* __restrict__ Bt,
                                          int m0, int n0,
                                          unsigned short (*Als)[64 * 64],
                                          unsigned short (*Bls)[128 * 64],
                                          f32x4 (*acc)[4]) {
  const int tid = threadIdx.x, lane = tid & 63, w = tid >> 6;
  const int wr = w >> 1, wc = w & 1;
  const int l = lane & 15, g = lane >> 4;
  const int r8 = lane >> 3;                 // row within 8-row stripe of one instr
  const int sce = ((lane & 7) ^ r8) * 8;    // inverse-swizzled source col (elems)
  const int sxr = (l & 7) * 8;              // read-side swizzle for row l (elems)

  // per wave per stage: 2 A-instrs + 4 B-instrs (each = 1KB = 8 rows x 64 elems)
  #define GSTAGE(buf, k0) do { \
      _Pragma("unroll") \
      for (int i_ = 0; i_ < 2; ++i_) { \
        int ia_ = w * 2 + i_; \
        gload16(A + (size_t)(m0 + ia_ * 8 + r8) * 512 + (k0) + sce, &Als[buf][ia_ * 512]); \
      } \
      _Pragma("unroll") \
      for (int i_ = 0; i_ < 4; ++i_) { \
        int ib_ = w * 4 + i_; \
        gload16(Bt + (size_t)(n0 + ib_ * 8 + r8) * 512 + (k0) + sce, &Bls[buf][ib_ * 512]); \
      } } while (0)

  GSTAGE(0, 0);
  GSTAGE(1, 64);
  int cur = 0;
  for (int t = 0; t < 8; ++t) {
    if (t < 7) { WAITV(6); } else { WAITV(0); }   // wait oldest stage only
    __builtin_amdgcn_s_barrier();
    if (t < 6) {
      int nb = cur + 2; if (nb >= 3) nb -= 3;
      GSTAGE(nb, (t + 2) * 64);
    }
    #pragma unroll
    for (int kk = 0; kk < 2; ++kk) {
      bf16x8 af[2], bf[4];
      #pragma unroll
      for (int m = 0; m < 2; ++m)
        af[m] = *(const bf16x8*)(&Als[cur][(wr * 32 + m * 16 + l) * 64 + ((kk * 32 + g * 8) ^ sxr)]);
      #pragma unroll
      for (int n = 0; n < 4; ++n)
        bf[n] = *(const bf16x8*)(&Bls[cur][(wc * 64 + n * 16 + l) * 64 + ((kk * 32 + g * 8) ^ sxr)]);
      #pragma unroll
      for (int m = 0; m < 2; ++m)
        #pragma unroll
        for (int n = 0; n < 4; ++n)
          acc[m][n] = mfma16(af[m], bf[n], acc[m][n]);
    }
    cur = cur == 2 ? 0 : cur + 1;
  }
  #undef GSTAGE
}

enum { EPI_BF16 = 0, EPI_F32RES = 2, EPI_LRELU = 3 };

template <int EPI>
__global__ __launch_bounds__(256) void gemm_kernel(const unsigned short* __restrict__ A,
                                                   const unsigned short* __restrict__ Bt,
                                                   const float* __restrict__ bias,
                                                   const float* __restrict__ res,
                                                   void* __restrict__ out) {
  __shared__ unsigned short Als[3][64 * 64];
  __shared__ unsigned short Bls[3][128 * 64];
  const int lane = threadIdx.x & 63, w = threadIdx.x >> 6;
  const int wr = w >> 1, wc = w & 1;
  const int l = lane & 15, g = lane >> 4;
  const int m0 = blockIdx.x * 64, n0 = blockIdx.y * 128;
  f32x4 acc[2][4] = {};
  gemm_core(A, Bt, m0, n0, Als, Bls, acc);

  #pragma unroll
  for (int m = 0; m < 2; ++m) {
    int grb = m0 + wr * 32 + m * 16 + g * 4;
    #pragma unroll
    for (int n = 0; n < 4; ++n) {
      int gc = n0 + wc * 64 + n * 16 + l;
      float bv = bias[gc];
      #pragma unroll
      for (int r = 0; r < 4; ++r) {
        int gr = grb + r;
        float v = acc[m][n][r] + bv;
        if (EPI == EPI_F32RES) {
          ((float*)out)[(size_t)gr * 512 + gc] = v + res[(size_t)gr * 512 + gc];
        } else if (EPI == EPI_BF16) {
          ((unsigned short*)out)[(size_t)gr * 512 + gc] = f2b(v);
        } else {  // EPI_LRELU
          v = v > 0.f ? v : 0.01f * v;
          ((unsigned short*)out)[(size_t)gr * 512 + gc] = f2b(v);
        }
      }
    }
  }
}

// QKV fused (grid.z selects projection); z=2 writes transposed V.
__global__ __launch_bounds__(256) void gemm_qkv_kernel(const unsigned short* __restrict__ qb,
                                                       const unsigned short* __restrict__ kb,
                                                       const unsigned short* __restrict__ vb,
                                                       const unsigned short* __restrict__ Wt,
                                                       const float* __restrict__ bq,
                                                       const float* __restrict__ bk,
                                                       const float* __restrict__ bv,
                                                       unsigned short* __restrict__ Qp,
                                                       unsigned short* __restrict__ Kp,
                                                       unsigned short* __restrict__ Vt) {
  __shared__ unsigned short Als[3][64 * 64];
  __shared__ unsigned short Bls[3][128 * 64];
  const int z = blockIdx.z;
  const unsigned short* A = z == 0 ? qb : z == 1 ? kb : vb;
  const unsigned short* B = Wt + (size_t)z * 512 * 512;
  const float* bias = z == 0 ? bq : z == 1 ? bk : bv;
  const int lane = threadIdx.x & 63, w = threadIdx.x >> 6;
  const int wr = w >> 1, wc = w & 1;
  const int l = lane & 15, g = lane >> 4;
  const int m0 = blockIdx.x * 64, n0 = blockIdx.y * 128;
  f32x4 acc[2][4] = {};
  gemm_core(A, B, m0, n0, Als, Bls, acc);

  #pragma unroll
  for (int m = 0; m < 2; ++m) {
    int grb = m0 + wr * 32 + m * 16 + g * 4;
    #pragma unroll
    for (int n = 0; n < 4; ++n) {
      int gc = n0 + wc * 64 + n * 16 + l;
      float bvl = bias[gc];
      #pragma unroll
      for (int r = 0; r < 4; ++r) {
        int gr = grb + r;
        float v = acc[m][n][r] + bvl;
        if (z == 0) {
          Qp[(size_t)gr * 512 + gc] = f2b(v);
        } else if (z == 1) {
          Kp[(size_t)gr * 512 + gc] = f2b(v);
        } else {  // transposed: Vt[(b*512+gc)][t]
          int b = gr >> 11, t = gr & 2047;
          Vt[((size_t)(b * 512 + gc) << 11) + t] = f2b(v);
        }
      }
    }
  }
}

// ---------------------------------------------------------------- flash attention
// Grid (bh, j): same-bh blocks share an XCD (linear id % 8 == bh % 8) -> K/V
// tiles read in lockstep become L2 hits. Triangle-paired: block j does q-tiles
// {31-j, j}. 3-buf K/V, counted vmcnt(4) (T4). Swapped QK^T, defer-rescale.
__global__ __launch_bounds__(256) void attn_kernel(const unsigned short* __restrict__ Q,
                                                   const unsigned short* __restrict__ K,
                                                   const unsigned short* __restrict__ Vt,
                                                   unsigned short* __restrict__ O) {
  __shared__ unsigned short Kls[3][64 * 64];
  __shared__ unsigned short Vls[3][64 * 64];
  __shared__ unsigned short Pls[4][16 * 64];
  const int tid = threadIdx.x, lane = tid & 63, w = tid >> 6;
  const int l = lane & 15, g = lane >> 4;
  const int j = blockIdx.y;            // 0..15
  const int bh = blockIdx.x;           // 0..31
  const int b = bh >> 3, h = bh & 7;
  const int sx = (l & 7) * 8;          // read-side swizzle (elems)
  const int n1 = 32 - j;               // steps in tile1
  const float SC2 = 0.125f * 1.44269504088896340736f;
  const float THR = 64.f;              // raw-score defer threshold

  const int r8 = lane >> 3;
  const int sce = ((lane & 7) ^ r8) * 8;  // inverse-swizzled source col (elems)

  #define STAGEKV(buf, kv0) do { \
      _Pragma("unroll") \
      for (int i_ = 0; i_ < 2; ++i_) { \
        int ii_ = w * 2 + i_; \
        int row_ = ii_ * 8 + r8; \
        gload16(K  + (size_t)(b * 2048 + (kv0) + row_) * 512 + h * 64 + sce, &Kls[buf][ii_ * 512]); \
        gload16(Vt + (size_t)(b * 512 + h * 64 + row_) * 2048 + (kv0) + sce, &Vls[buf][ii_ * 512]); \
      } } while (0)

  int tile = 31 - j;
  int q0 = tile * 64 + w * 16;
  bf16x8 qf[2];
  #pragma unroll
  for (int kf = 0; kf < 2; ++kf)
    qf[kf] = *(const bf16x8*)(Q + (size_t)(b * 2048 + q0 + l) * 512 + h * 64 + kf * 32 + g * 8);

  float mrun = -1e30f, lrun = 0.f;
  f32x4 o[4] = {};

  STAGEKV(0, 0);
  STAGEKV(1, 64);
  int cur = 0;

  for (int s = 0; s <= 32; ++s) {
    if (s < 32) { WAITV(4); } else { WAITV(0); }
    __builtin_amdgcn_s_barrier();
    if (s + 2 <= 32) {
      int sp = s + 2;
      int kbp = sp < n1 ? sp : sp - n1;
      int nb = cur + 2; if (nb >= 3) nb -= 3;
      STAGEKV(nb, kbp * 64);
    }
    int kb = s < n1 ? s : s - n1;
    int kv0 = kb * 64;

    // S^T (raw): lane holds S[q=q0+l][kv = kv0 + t*16 + g*4 + r]
    f32x4 st[4];
    #pragma unroll
    for (int t = 0; t < 4; ++t) {
      st[t] = f32x4{0.f, 0.f, 0.f, 0.f};
      #pragma unroll
      for (int kf = 0; kf < 2; ++kf) {
        bf16x8 kfr = *(const bf16x8*)(&Kls[cur][(t * 16 + l) * 64 + ((kf * 32 + g * 8) ^ sx)]);
        st[t] = mfma16(kfr, qf[kf], st[t]);
      }
    }
    if (kb == tile) {   // uniform branch: only diagonal steps mask
      const int qrow = q0 + l;
      #pragma unroll
      for (int t = 0; t < 4; ++t)
        #pragma unroll
        for (int r = 0; r < 4; ++r)
          if (kv0 + t * 16 + g * 4 + r > qrow) st[t][r] = -1e30f;
    }

    float mx = fmaxf(fmaxf(fmaxf(st[0][0], st[0][1]), fmaxf(st[0][2], st[0][3])),
                     fmaxf(fmaxf(st[1][0], st[1][1]), fmaxf(st[1][2], st[1][3])));
    mx = fmaxf(mx, fmaxf(fmaxf(fmaxf(st[2][0], st[2][1]), fmaxf(st[2][2], st[2][3])),
                         fmaxf(fmaxf(st[3][0], st[3][1]), fmaxf(st[3][2], st[3][3]))));
    mx = fmaxf(mx, __shfl_xor(mx, 16, 64));
    mx = fmaxf(mx, __shfl_xor(mx, 32, 64));

    if (!__all(mx <= mrun + THR)) {   // T13 defer-rescale
      float nm = fmaxf(mrun, mx);
      float alpha = exp2f((mrun - nm) * SC2);
      mrun = nm;
      lrun *= alpha;
      #pragma unroll
      for (int r = 0; r < 4; ++r) {
        float ar = __shfl(alpha, g * 4 + r, 64);
        #pragma unroll
        for (int n = 0; n < 4; ++n) o[n][r] *= ar;
      }
    }

    float mS = mrun * SC2;
    float rs = 0.f;
    #pragma unroll
    for (int t = 0; t < 4; ++t)
      #pragma unroll
      for (int r = 0; r < 4; ++r) {
        float p = exp2f(fmaf(st[t][r], SC2, -mS));
        st[t][r] = p;
        rs += p;
      }
    rs += __shfl_xor(rs, 16, 64);
    rs += __shfl_xor(rs, 32, 64);
    lrun += rs;

    // P pack -> swizzled per-wave LDS [16][64], then PV
    #pragma unroll
    for (int t = 0; t < 4; ++t) {
      uint2 u;
      u.x = pkbf(st[t][0], st[t][1]);
      u.y = pkbf(st[t][2], st[t][3]);
      *(uint2*)(&Pls[w][l * 64 + ((t * 16 + g * 4) ^ sx)]) = u;
    }
    #pragma unroll
    for (int kf = 0; kf < 2; ++kf) {
      bf16x8 pa = *(const bf16x8*)(&Pls[w][l * 64 + ((kf * 32 + g * 8) ^ sx)]);
      #pragma unroll
      for (int n = 0; n < 4; ++n) {
        bf16x8 vf = *(const bf16x8*)(&Vls[cur][(n * 16 + l) * 64 + ((kf * 32 + g * 8) ^ sx)]);
        o[n] = mfma16(pa, vf, o[n]);
      }
    }

    if (s == n1 - 1) {
      // finish tile1: write O, reset, load tile2's Q
      float li = 1.f / lrun;
      #pragma unroll
      for (int r = 0; r < 4; ++r) {
        float lir = __shfl(li, g * 4 + r, 64);
        #pragma unroll
        for (int n = 0; n < 4; ++n)
          O[(size_t)(b * 2048 + q0 + g * 4 + r) * 512 + h * 64 + n * 16 + l] =
              f2b(o[n][r] * lir);
      }
      tile = j;
      q0 = tile * 64 + w * 16;
      #pragma unroll
      for (int kf = 0; kf < 2; ++kf)
        qf[kf] = *(const bf16x8*)(Q + (size_t)(b * 2048 + q0 + l) * 512 + h * 64 + kf * 32 + g * 8);
      mrun = -1e30f; lrun = 0.f;
      #pragma unroll
      for (int n = 0; n < 4; ++n) o[n] = f32x4{0.f, 0.f, 0.f, 0.f};
    }
    cur = cur == 2 ? 0 : cur + 1;
  }

  float li = 1.f / lrun;
  #pragma unroll
  for (int r = 0; r < 4; ++r) {
    float lir = __shfl(li, g * 4 + r, 64);
    #pragma unroll
    for (int n = 0; n < 4; ++n)
      O[(size_t)(b * 2048 + q0 + g * 4 + r) * 512 + h * 64 + n * 16 + l] =
          f2b(o[n][r] * lir);
  }
  #undef STAGEKV
}

// ---------------------------------------------------------------- LayerNorm (wave per row)
template <int WRITE_BF16>
__global__ __launch_bounds__(256) void ln_kernel(const float* __restrict__ X,
                                                 const float* __restrict__ g,
                                                 const float* __restrict__ be,
                                                 float* __restrict__ Yf,
                                                 unsigned short* __restrict__ Yb) {
  int row = blockIdx.x * 4 + (threadIdx.x >> 6);
  int lane = threadIdx.x & 63;
  const float* x = X + (size_t)row * 512;
  float4 v0 = *(const float4*)(x + lane * 4);
  float4 v1 = *(const float4*)(x + 256 + lane * 4);
  float s = v0.x + v0.y + v0.z + v0.w + v1.x + v1.y + v1.z + v1.w;
  #pragma unroll
  for (int t = 1; t < 64; t <<= 1) s += __shfl_xor(s, t, 64);
  float mu = s * (1.f / 512.f);
  float q = 0.f;
  q += (v0.x - mu) * (v0.x - mu); q += (v0.y - mu) * (v0.y - mu);
  q += (v0.z - mu) * (v0.z - mu); q += (v0.w - mu) * (v0.w - mu);
  q += (v1.x - mu) * (v1.x - mu); q += (v1.y - mu) * (v1.y - mu);
  q += (v1.z - mu) * (v1.z - mu); q += (v1.w - mu) * (v1.w - mu);
  #pragma unroll
  for (int t = 1; t < 64; t <<= 1) q += __shfl_xor(q, t, 64);
  float rstd = rsqrtf(q * (1.f / 512.f) + 1e-5f);

  float4 g0 = *(const float4*)(g + lane * 4);
  float4 g1 = *(const float4*)(g + 256 + lane * 4);
  float4 b0 = *(const float4*)(be + lane * 4);
  float4 b1 = *(const float4*)(be + 256 + lane * 4);
  float4 y0, y1;
  y0.x = (v0.x - mu) * rstd * g0.x + b0.x; y0.y = (v0.y - mu) * rstd * g0.y + b0.y;
  y0.z = (v0.z - mu) * rstd * g0.z + b0.z; y0.w = (v0.w - mu) * rstd * g0.w + b0.w;
  y1.x = (v1.x - mu) * rstd * g1.x + b1.x; y1.y = (v1.y - mu) * rstd * g1.y + b1.y;
  y1.z = (v1.z - mu) * rstd * g1.z + b1.z; y1.w = (v1.w - mu) * rstd * g1.w + b1.w;
  if (Yf) {
    *(float4*)(Yf + (size_t)row * 512 + lane * 4) = y0;
    *(float4*)(Yf + (size_t)row * 512 + 256 + lane * 4) = y1;
  }
  if (WRITE_BF16) {
    ushort4 u0, u1;
    u0.x = f2b(y0.x); u0.y = f2b(y0.y); u0.z = f2b(y0.z); u0.w = f2b(y0.w);
    u1.x = f2b(y1.x); u1.y = f2b(y1.y); u1.z = f2b(y1.z); u1.w = f2b(y1.w);
    *(ushort4*)(Yb + (size_t)row * 512 + lane * 4) = u0;
    *(ushort4*)(Yb + (size_t)row * 512 + 256 + lane * 4) = u1;
  }
}

// ---------------------------------------------------------------- launch
extern "C" void kernel_launch(void* const* d_in, const int* in_sizes, int n_in,
                              void* d_out, int out_size, void* d_ws, size_t ws_size,
                              hipStream_t stream) {
  const float* q_in = (const float*)d_in[0];
  const float* k_in = (const float*)d_in[1];
  const float* v_in = (const float*)d_in[2];
  const float* Wq = (const float*)d_in[3];  const float* bq = (const float*)d_in[4];
  const float* Wk = (const float*)d_in[5];  const float* bk = (const float*)d_in[6];
  const float* Wv = (const float*)d_in[7];  const float* bv = (const float*)d_in[8];
  const float* Wo = (const float*)d_in[9];  const float* bo = (const float*)d_in[10];
  const float* Wh = (const float*)d_in[11]; const float* bh = (const float*)d_in[12];
  const float* W2 = (const float*)d_in[13]; const float* b2 = (const float*)d_in[14];
  const float* g1 = (const float*)d_in[15]; const float* be1 = (const float*)d_in[16];
  const float* g2 = (const float*)d_in[17]; const float* be2 = (const float*)d_in[18];

  char* ws = (char*)d_ws;
  const size_t MD2 = (size_t)MTOT * 512 * 2;   // 8 MB bf16 buffer
  const size_t W1  = (size_t)512 * 512 * 2;
  const size_t MD4 = (size_t)MTOT * 512 * 4;   // 16 MB f32 buffer
  unsigned short* qb_  = (unsigned short*)(ws);
  unsigned short* kb_  = (unsigned short*)(ws + MD2);
  unsigned short* vb_  = (unsigned short*)(ws + 2 * MD2);
  unsigned short* Qp   = (unsigned short*)(ws + 3 * MD2);
  unsigned short* Kp   = (unsigned short*)(ws + 4 * MD2);
  unsigned short* Vt   = (unsigned short*)(ws + 5 * MD2);
  unsigned short* Wt   = (unsigned short*)(ws + 6 * MD2);  // 6 matrices
  float*          hy   = (float*)(ws + 6 * MD2 + 6 * W1);
  float*          ln1f = (float*)(ws + 6 * MD2 + 6 * W1 + MD4);
  // aliases (consumers done before producers write):
  unsigned short* attn = vb_;   // vb consumed by QKV gemm before attn runs
  unsigned short* ln1b = qb_;
  unsigned short* f1   = kb_;

  cast3_kernel<<<dim3(MTOT * 512 / 2048, 3), 256, 0, stream>>>(q_in, k_in, v_in, qb_, kb_, vb_);
  transpose6_kernel<<<dim3(16, 16, 6), 256, 0, stream>>>(Wq, Wk, Wv, Wo, Wh, W2, Wt);

  // fused QKV projections (z: 0=Q,1=K,2=V-transposed)
  gemm_qkv_kernel<<<dim3(MTOT / 64, 4, 3), 256, 0, stream>>>(
      qb_, kb_, vb_, Wt, bq, bk, bv, Qp, Kp, Vt);

  // attention: grid (bh, j) for XCD locality
  attn_kernel<<<dim3(BATCH * NH, 16), 256, 0, stream>>>(Qp, Kp, Vt, attn);

  dim3 gg(MTOT / 64, 4);
  // h = attn @ Wo + bo + q
  gemm_kernel<EPI_F32RES><<<gg, 256, 0, stream>>>(attn, Wt + 3 * 512 * 512, bo, q_in, hy);
  ln_kernel<1><<<MTOT / 4, 256, 0, stream>>>(hy, g1, be1, ln1f, ln1b);
  // f1 = leaky(ln1 @ Wh + bh)
  gemm_kernel<EPI_LRELU><<<gg, 256, 0, stream>>>(ln1b, Wt + 4 * 512 * 512, bh, nullptr, f1);
  // y = f1 @ W2 + b2 + ln1
  gemm_kernel<EPI_F32RES><<<gg, 256, 0, stream>>>(f1, Wt + 5 * 512 * 512, b2, ln1f, hy);
  ln_kernel<0><<<MTOT / 4, 256, 0, stream>>>(hy, g2, be2, (float*)d_out, nullptr);
}

// Round 6
// 255.876 us; speedup vs baseline: 1.4437x; 1.0009x over previous
//
#include <hip/hip_runtime.h>
#include <math.h>

#define DIN   512
#define TSEQ  2048
#define BATCH 4
#define NH    8
#define DHEAD 64
#define MTOT  8192   // BATCH*TSEQ

typedef __attribute__((ext_vector_type(8))) __bf16 bf16x8;
typedef __attribute__((ext_vector_type(8))) short  s16x8;
typedef __attribute__((ext_vector_type(4))) float  f32x4;

__device__ __forceinline__ unsigned short f2b(float f) {
  union { float f; unsigned int u; } c; c.f = f;
  unsigned int r = (c.u + 0x7fffu + ((c.u >> 16) & 1u)) >> 16;
  return (unsigned short)r;
}

__device__ __forceinline__ unsigned int pkbf(float a, float b) {
  union { __bf16 h[2]; unsigned int u; } c;
  c.h[0] = (__bf16)a; c.h[1] = (__bf16)b; return c.u;
}

__device__ __forceinline__ f32x4 mfma16(bf16x8 a, bf16x8 b, f32x4 c) {
  return __builtin_amdgcn_mfma_f32_16x16x32_bf16(a, b, c, 0, 0, 0);
}

// async global->LDS, 16B per lane; LDS dest = wave-uniform base + lane*16.
__device__ __forceinline__ void gload16(const void* gsrc, void* ldsbase) {
  __builtin_amdgcn_global_load_lds(
      (const __attribute__((address_space(1))) unsigned int*)gsrc,
      (__attribute__((address_space(3))) unsigned int*)(unsigned int)(unsigned long long)ldsbase,
      16, 0, 0);
}

#define VMCNT0_BARRIER() do { \
    asm volatile("s_waitcnt vmcnt(0)" ::: "memory"); \
    __builtin_amdgcn_s_barrier(); } while (0)

// ---------------------------------------------------------------- cast f32->bf16 (3 tensors)
__global__ __launch_bounds__(256) void cast3_kernel(const float* __restrict__ q,
                                                    const float* __restrict__ k,
                                                    const float* __restrict__ v,
                                                    unsigned short* __restrict__ oq,
                                                    unsigned short* __restrict__ ok,
                                                    unsigned short* __restrict__ ov) {
  const float* in = blockIdx.y == 0 ? q : blockIdx.y == 1 ? k : v;
  unsigned short* out = blockIdx.y == 0 ? oq : blockIdx.y == 1 ? ok : ov;
  int i = (blockIdx.x * 256 + threadIdx.x) * 8;
  float4 a = *(const float4*)(in + i);
  float4 b = *(const float4*)(in + i + 4);
  ushort4 u0, u1;
  u0.x = f2b(a.x); u0.y = f2b(a.y); u0.z = f2b(a.z); u0.w = f2b(a.w);
  u1.x = f2b(b.x); u1.y = f2b(b.y); u1.z = f2b(b.z); u1.w = f2b(b.w);
  *(ushort4*)(out + i) = u0;
  *(ushort4*)(out + i + 4) = u1;
}

// ---------------------------- 6x W [K][N] f32 -> Wt [N][K] bf16 (one launch)
__global__ __launch_bounds__(256) void transpose6_kernel(const float* __restrict__ w0,
                                                         const float* __restrict__ w1,
                                                         const float* __restrict__ w2,
                                                         const float* __restrict__ w3,
                                                         const float* __restrict__ w4,
                                                         const float* __restrict__ w5,
                                                         unsigned short* __restrict__ Wt) {
  const float* W;
  switch (blockIdx.z) {
    case 0: W = w0; break; case 1: W = w1; break; case 2: W = w2; break;
    case 3: W = w3; break; case 4: W = w4; break; default: W = w5; break;
  }
  unsigned short* dst = Wt + (size_t)blockIdx.z * 512 * 512;
  __shared__ float tile[32][33];
  int bx = blockIdx.x * 32, by = blockIdx.y * 32;
  int tx = threadIdx.x & 31, ty = threadIdx.x >> 5;
  #pragma unroll
  for (int yy = ty; yy < 32; yy += 8)
    tile[yy][tx] = W[(size_t)(by + yy) * DIN + bx + tx];
  __syncthreads();
  #pragma unroll
  for (int yy = ty; yy < 32; yy += 8)
    dst[(size_t)(bx + yy) * DIN + by + tx] = f2b(tile[tx][yy]);
}

// ---------------------------------------------------------------- GEMM core
// BM=64, BN=128, BK=64, 8 K-steps; 4 waves (2x2); 2-buf LDS (48KB -> 3 blk/CU),
// stage-next -> compute-cur -> drain+barrier (R4-proven), XOR-swizzled LDS (T2).
__device__ __forceinline__ void gemm_core(const unsigned short* __restrict__ A,
                                          const unsigned short* __restrict__ Bt,
                                          int m0, int n0,
                                          unsigned short (*Als)[64 * 64],
                                          unsigned short (*Bls)[128 * 64],
                                          f32x4 (*acc)[4]) {
  const int tid = threadIdx.x, lane = tid & 63, w = tid >> 6;
  const int wr = w >> 1, wc = w & 1;
  const int l = lane & 15, g = lane >> 4;
  const int r8 = lane >> 3;                 // row within 8-row stripe of one instr
  const int sce = ((lane & 7) ^ r8) * 8;    // inverse-swizzled source col (elems)
  const int sxr = (l & 7) * 8;              // read-side swizzle for row l (elems)

  // per wave per stage: 2 A-instrs + 4 B-instrs (each = 1KB = 8 rows x 64 elems)
  #define GSTAGE(buf, k0) do { \
      _Pragma("unroll") \
      for (int i_ = 0; i_ < 2; ++i_) { \
        int ia_ = w * 2 + i_; \
        gload16(A + (size_t)(m0 + ia_ * 8 + r8) * 512 + (k0) + sce, &Als[buf][ia_ * 512]); \
      } \
      _Pragma("unroll") \
      for (int i_ = 0; i_ < 4; ++i_) { \
        int ib_ = w * 4 + i_; \
        gload16(Bt + (size_t)(n0 + ib_ * 8 + r8) * 512 + (k0) + sce, &Bls[buf][ib_ * 512]); \
      } } while (0)

  GSTAGE(0, 0);
  VMCNT0_BARRIER();
  for (int t = 0; t < 8; ++t) {
    int cur = t & 1;
    if (t < 7) GSTAGE(cur ^ 1, (t + 1) * 64);   // issue next-tile loads FIRST
    #pragma unroll
    for (int kk = 0; kk < 2; ++kk) {
      bf16x8 af[2], bf[4];
      #pragma unroll
      for (int m = 0; m < 2; ++m)
        af[m] = *(const bf16x8*)(&Als[cur][(wr * 32 + m * 16 + l) * 64 + ((kk * 32 + g * 8) ^ sxr)]);
      #pragma unroll
      for (int n = 0; n < 4; ++n)
        bf[n] = *(const bf16x8*)(&Bls[cur][(wc * 64 + n * 16 + l) * 64 + ((kk * 32 + g * 8) ^ sxr)]);
      #pragma unroll
      for (int m = 0; m < 2; ++m)
        #pragma unroll
        for (int n = 0; n < 4; ++n)
          acc[m][n] = mfma16(af[m], bf[n], acc[m][n]);
    }
    VMCNT0_BARRIER();
  }
  #undef GSTAGE
}

enum { EPI_BF16 = 0, EPI_F32RES = 2, EPI_LRELU = 3 };

template <int EPI>
__global__ __launch_bounds__(256) void gemm_kernel(const unsigned short* __restrict__ A,
                                                   const unsigned short* __restrict__ Bt,
                                                   const float* __restrict__ bias,
                                                   const float* __restrict__ res,
                                                   void* __restrict__ out) {
  __shared__ unsigned short Als[2][64 * 64];
  __shared__ unsigned short Bls[2][128 * 64];
  const int lane = threadIdx.x & 63, w = threadIdx.x >> 6;
  const int wr = w >> 1, wc = w & 1;
  const int l = lane & 15, g = lane >> 4;
  const int m0 = blockIdx.x * 64, n0 = blockIdx.y * 128;
  f32x4 acc[2][4] = {};
  gemm_core(A, Bt, m0, n0, Als, Bls, acc);

  #pragma unroll
  for (int m = 0; m < 2; ++m) {
    int grb = m0 + wr * 32 + m * 16 + g * 4;
    #pragma unroll
    for (int n = 0; n < 4; ++n) {
      int gc = n0 + wc * 64 + n * 16 + l;
      float bv = bias[gc];
      #pragma unroll
      for (int r = 0; r < 4; ++r) {
        int gr = grb + r;
        float v = acc[m][n][r] + bv;
        if (EPI == EPI_F32RES) {
          ((float*)out)[(size_t)gr * 512 + gc] = v + res[(size_t)gr * 512 + gc];
        } else if (EPI == EPI_BF16) {
          ((unsigned short*)out)[(size_t)gr * 512 + gc] = f2b(v);
        } else {  // EPI_LRELU
          v = v > 0.f ? v : 0.01f * v;
          ((unsigned short*)out)[(size_t)gr * 512 + gc] = f2b(v);
        }
      }
    }
  }
}

// QKV fused (grid.z selects projection); z=2 writes transposed V.
__global__ __launch_bounds__(256) void gemm_qkv_kernel(const unsigned short* __restrict__ qb,
                                                       const unsigned short* __restrict__ kb,
                                                       const unsigned short* __restrict__ vb,
                                                       const unsigned short* __restrict__ Wt,
                                                       const float* __restrict__ bq,
                                                       const float* __restrict__ bk,
                                                       const float* __restrict__ bv,
                                                       unsigned short* __restrict__ Qp,
                                                       unsigned short* __restrict__ Kp,
                                                       unsigned short* __restrict__ Vt) {
  __shared__ unsigned short Als[2][64 * 64];
  __shared__ unsigned short Bls[2][128 * 64];
  const int z = blockIdx.z;
  const unsigned short* A = z == 0 ? qb : z == 1 ? kb : vb;
  const unsigned short* B = Wt + (size_t)z * 512 * 512;
  const float* bias = z == 0 ? bq : z == 1 ? bk : bv;
  const int lane = threadIdx.x & 63, w = threadIdx.x >> 6;
  const int wr = w >> 1, wc = w & 1;
  const int l = lane & 15, g = lane >> 4;
  const int m0 = blockIdx.x * 64, n0 = blockIdx.y * 128;
  f32x4 acc[2][4] = {};
  gemm_core(A, B, m0, n0, Als, Bls, acc);

  #pragma unroll
  for (int m = 0; m < 2; ++m) {
    int grb = m0 + wr * 32 + m * 16 + g * 4;
    #pragma unroll
    for (int n = 0; n < 4; ++n) {
      int gc = n0 + wc * 64 + n * 16 + l;
      float bvl = bias[gc];
      #pragma unroll
      for (int r = 0; r < 4; ++r) {
        int gr = grb + r;
        float v = acc[m][n][r] + bvl;
        if (z == 0) {
          Qp[(size_t)gr * 512 + gc] = f2b(v);
        } else if (z == 1) {
          Kp[(size_t)gr * 512 + gc] = f2b(v);
        } else {  // transposed: Vt[(b*512+gc)][t]
          int b = gr >> 11, t = gr & 2047;
          Vt[((size_t)(b * 512 + gc) << 11) + t] = f2b(v);
        }
      }
    }
  }
}

// ---------------------------------------------------------------- flash attention
// Grid (bh=32, qtile=32): one 64-row q-tile per block (1024 blocks, 4 blk/CU);
// qt descending so longest blocks dispatch first; same-bh blocks share an XCD.
// 2-buf K/V via global_load_lds (swizzled); swapped QK^T; defer-rescale; row
// sums via ones-MFMA (denominator from bf16 P, consistent with PV numerator).
__global__ __launch_bounds__(256) void attn_kernel(const unsigned short* __restrict__ Q,
                                                   const unsigned short* __restrict__ K,
                                                   const unsigned short* __restrict__ Vt,
                                                   unsigned short* __restrict__ O) {
  __shared__ unsigned short Kls[2][64 * 64];
  __shared__ unsigned short Vls[2][64 * 64];
  __shared__ unsigned short Pls[4][16 * 64];
  const int tid = threadIdx.x, lane = tid & 63, w = tid >> 6;
  const int l = lane & 15, g = lane >> 4;
  const int bh = blockIdx.x;           // 0..31  (id%8 = bh%8 -> XCD locality)
  const int qt = (int)gridDim.y - 1 - (int)blockIdx.y;  // 0..31, longest first
  const int b = bh >> 3, h = bh & 7;
  const int sx = (l & 7) * 8;          // read-side swizzle (elems)
  const float SC2 = 0.125f * 1.44269504088896340736f;
  const float THR = 64.f;              // raw-score defer threshold (~e^8 bound)

  const int r8 = lane >> 3;
  const int sce = ((lane & 7) ^ r8) * 8;  // inverse-swizzled source col (elems)

  #define STAGEKV(buf, kv0) do { \
      _Pragma("unroll") \
      for (int i_ = 0; i_ < 2; ++i_) { \
        int ii_ = w * 2 + i_; \
        int row_ = ii_ * 8 + r8; \
        gload16(K  + (size_t)(b * 2048 + (kv0) + row_) * 512 + h * 64 + sce, &Kls[buf][ii_ * 512]); \
        gload16(Vt + (size_t)(b * 512 + h * 64 + row_) * 2048 + (kv0) + sce, &Vls[buf][ii_ * 512]); \
      } } while (0)

  const int q0 = qt * 64 + w * 16;
  bf16x8 qf[2];
  #pragma unroll
  for (int kf = 0; kf < 2; ++kf)
    qf[kf] = *(const bf16x8*)(Q + (size_t)(b * 2048 + q0 + l) * 512 + h * 64 + kf * 32 + g * 8);

  bf16x8 vones;
  #pragma unroll
  for (int i = 0; i < 8; ++i) vones[i] = (__bf16)1.0f;

  float mrun = -1e30f;
  f32x4 o[4] = {};
  f32x4 os = {0.f, 0.f, 0.f, 0.f};   // row sums (rows g*4+r) via ones-MFMA

  STAGEKV(0, 0);
  VMCNT0_BARRIER();

  for (int s = 0; s <= qt; ++s) {
    int cur = s & 1;
    if (s < qt) STAGEKV(cur ^ 1, (s + 1) * 64);
    int kv0 = s * 64;

    // S^T (raw): lane holds S[q=q0+l][kv = kv0 + t*16 + g*4 + r]
    f32x4 st[4];
    #pragma unroll
    for (int t = 0; t < 4; ++t) {
      st[t] = f32x4{0.f, 0.f, 0.f, 0.f};
      #pragma unroll
      for (int kf = 0; kf < 2; ++kf) {
        bf16x8 kfr = *(const bf16x8*)(&Kls[cur][(t * 16 + l) * 64 + ((kf * 32 + g * 8) ^ sx)]);
        st[t] = mfma16(kfr, qf[kf], st[t]);
      }
    }
    if (s == qt) {   // uniform branch: only the diagonal step masks
      const int qrow = q0 + l;
      #pragma unroll
      for (int t = 0; t < 4; ++t)
        #pragma unroll
        for (int r = 0; r < 4; ++r)
          if (kv0 + t * 16 + g * 4 + r > qrow) st[t][r] = -1e30f;
    }

    // row max: nested triples (max3-fusable) then 2 shfls across g-lanes
    float mx = fmaxf(
        fmaxf(fmaxf(fmaxf(st[0][0], st[0][1]), st[0][2]),
              fmaxf(fmaxf(st[0][3], st[1][0]), st[1][1])),
        fmaxf(fmaxf(fmaxf(st[1][2], st[1][3]), st[2][0]),
              fmaxf(fmaxf(st[2][1], st[2][2]), st[2][3])));
    mx = fmaxf(mx, fmaxf(fmaxf(st[3][0], st[3][1]), fmaxf(st[3][2], st[3][3])));
    mx = fmaxf(mx, __shfl_xor(mx, 16, 64));
    mx = fmaxf(mx, __shfl_xor(mx, 32, 64));

    if (!__all(mx <= mrun + THR)) {   // T13 defer-rescale
      float nm = fmaxf(mrun, mx);
      float alpha = exp2f((mrun - nm) * SC2);
      mrun = nm;
      #pragma unroll
      for (int r = 0; r < 4; ++r) {
        float ar = __shfl(alpha, g * 4 + r, 64);
        #pragma unroll
        for (int n = 0; n < 4; ++n) o[n][r] *= ar;
        os[r] *= ar;
      }
    }

    float mS = mrun * SC2;
    #pragma unroll
    for (int t = 0; t < 4; ++t)
      #pragma unroll
      for (int r = 0; r < 4; ++r)
        st[t][r] = exp2f(fmaf(st[t][r], SC2, -mS));

    // P pack -> swizzled per-wave LDS [16][64], then PV (+ ones column for sums)
    #pragma unroll
    for (int t = 0; t < 4; ++t) {
      uint2 u;
      u.x = pkbf(st[t][0], st[t][1]);
      u.y = pkbf(st[t][2], st[t][3]);
      *(uint2*)(&Pls[w][l * 64 + ((t * 16 + g * 4) ^ sx)]) = u;
    }
    #pragma unroll
    for (int kf = 0; kf < 2; ++kf) {
      bf16x8 pa = *(const bf16x8*)(&Pls[w][l * 64 + ((kf * 32 + g * 8) ^ sx)]);
      #pragma unroll
      for (int n = 0; n < 4; ++n) {
        bf16x8 vf = *(const bf16x8*)(&Vls[cur][(n * 16 + l) * 64 + ((kf * 32 + g * 8) ^ sx)]);
        o[n] = mfma16(pa, vf, o[n]);
      }
      os = mfma16(pa, vones, os);
    }

    VMCNT0_BARRIER();
  }

  #pragma unroll
  for (int r = 0; r < 4; ++r) {
    float lir = 1.f / os[r];   // row g*4+r sum, already per-lane — no shfl
    #pragma unroll
    for (int n = 0; n < 4; ++n)
      O[(size_t)(b * 2048 + q0 + g * 4 + r) * 512 + h * 64 + n * 16 + l] =
          f2b(o[n][r] * lir);
  }
  #undef STAGEKV
}

// ---------------------------------------------------------------- LayerNorm (wave per row)
template <int WRITE_BF16>
__global__ __launch_bounds__(256) void ln_kernel(const float* __restrict__ X,
                                                 const float* __restrict__ g,
                                                 const float* __restrict__ be,
                                                 float* __restrict__ Yf,
                                                 unsigned short* __restrict__ Yb) {
  int row = blockIdx.x * 4 + (threadIdx.x >> 6);
  int lane = threadIdx.x & 63;
  const float* x = X + (size_t)row * 512;
  float4 v0 = *(const float4*)(x + lane * 4);
  float4 v1 = *(const float4*)(x + 256 + lane * 4);
  float s = v0.x + v0.y + v0.z + v0.w + v1.x + v1.y + v1.z + v1.w;
  #pragma unroll
  for (int t = 1; t < 64; t <<= 1) s += __shfl_xor(s, t, 64);
  float mu = s * (1.f / 512.f);
  float q = 0.f;
  q += (v0.x - mu) * (v0.x - mu); q += (v0.y - mu) * (v0.y - mu);
  q += (v0.z - mu) * (v0.z - mu); q += (v0.w - mu) * (v0.w - mu);
  q += (v1.x - mu) * (v1.x - mu); q += (v1.y - mu) * (v1.y - mu);
  q += (v1.z - mu) * (v1.z - mu); q += (v1.w - mu) * (v1.w - mu);
  #pragma unroll
  for (int t = 1; t < 64; t <<= 1) q += __shfl_xor(q, t, 64);
  float rstd = rsqrtf(q * (1.f / 512.f) + 1e-5f);

  float4 g0 = *(const float4*)(g + lane * 4);
  float4 g1 = *(const float4*)(g + 256 + lane * 4);
  float4 b0 = *(const float4*)(be + lane * 4);
  float4 b1 = *(const float4*)(be + 256 + lane * 4);
  float4 y0, y1;
  y0.x = (v0.x - mu) * rstd * g0.x + b0.x; y0.y = (v0.y - mu) * rstd * g0.y + b0.y;
  y0.z = (v0.z - mu) * rstd * g0.z + b0.z; y0.w = (v0.w - mu) * rstd * g0.w + b0.w;
  y1.x = (v1.x - mu) * rstd * g1.x + b1.x; y1.y = (v1.y - mu) * rstd * g1.y + b1.y;
  y1.z = (v1.z - mu) * rstd * g1.z + b1.z; y1.w = (v1.w - mu) * rstd * g1.w + b1.w;
  if (Yf) {
    *(float4*)(Yf + (size_t)row * 512 + lane * 4) = y0;
    *(float4*)(Yf + (size_t)row * 512 + 256 + lane * 4) = y1;
  }
  if (WRITE_BF16) {
    ushort4 u0, u1;
    u0.x = f2b(y0.x); u0.y = f2b(y0.y); u0.z = f2b(y0.z); u0.w = f2b(y0.w);
    u1.x = f2b(y1.x); u1.y = f2b(y1.y); u1.z = f2b(y1.z); u1.w = f2b(y1.w);
    *(ushort4*)(Yb + (size_t)row * 512 + lane * 4) = u0;
    *(ushort4*)(Yb + (size_t)row * 512 + 256 + lane * 4) = u1;
  }
}

// ---------------------------------------------------------------- launch
extern "C" void kernel_launch(void* const* d_in, const int* in_sizes, int n_in,
                              void* d_out, int out_size, void* d_ws, size_t ws_size,
                              hipStream_t stream) {
  const float* q_in = (const float*)d_in[0];
  const float* k_in = (const float*)d_in[1];
  const float* v_in = (const float*)d_in[2];
  const float* Wq = (const float*)d_in[3];  const float* bq = (const float*)d_in[4];
  const float* Wk = (const float*)d_in[5];  const float* bk = (const float*)d_in[6];
  const float* Wv = (const float*)d_in[7];  const float* bv = (const float*)d_in[8];
  const float* Wo = (const float*)d_in[9];  const float* bo = (const float*)d_in[10];
  const float* Wh = (const float*)d_in[11]; const float* bh = (const float*)d_in[12];
  const float* W2 = (const float*)d_in[13]; const float* b2 = (const float*)d_in[14];
  const float* g1 = (const float*)d_in[15]; const float* be1 = (const float*)d_in[16];
  const float* g2 = (const float*)d_in[17]; const float* be2 = (const float*)d_in[18];

  char* ws = (char*)d_ws;
  const size_t MD2 = (size_t)MTOT * 512 * 2;   // 8 MB bf16 buffer
  const size_t W1  = (size_t)512 * 512 * 2;
  const size_t MD4 = (size_t)MTOT * 512 * 4;   // 16 MB f32 buffer
  unsigned short* qb_  = (unsigned short*)(ws);
  unsigned short* kb_  = (unsigned short*)(ws + MD2);
  unsigned short* vb_  = (unsigned short*)(ws + 2 * MD2);
  unsigned short* Qp   = (unsigned short*)(ws + 3 * MD2);
  unsigned short* Kp   = (unsigned short*)(ws + 4 * MD2);
  unsigned short* Vt   = (unsigned short*)(ws + 5 * MD2);
  unsigned short* Wt   = (unsigned short*)(ws + 6 * MD2);  // 6 matrices
  float*          hy   = (float*)(ws + 6 * MD2 + 6 * W1);
  float*          ln1f = (float*)(ws + 6 * MD2 + 6 * W1 + MD4);
  // aliases (consumers done before producers write):
  unsigned short* attn = vb_;   // vb consumed by QKV gemm before attn runs
  unsigned short* ln1b = qb_;
  unsigned short* f1   = kb_;

  cast3_kernel<<<dim3(MTOT * 512 / 2048, 3), 256, 0, stream>>>(q_in, k_in, v_in, qb_, kb_, vb_);
  transpose6_kernel<<<dim3(16, 16, 6), 256, 0, stream>>>(Wq, Wk, Wv, Wo, Wh, W2, Wt);

  // fused QKV projections (z: 0=Q,1=K,2=V-transposed)
  gemm_qkv_kernel<<<dim3(MTOT / 64, 4, 3), 256, 0, stream>>>(
      qb_, kb_, vb_, Wt, bq, bk, bv, Qp, Kp, Vt);

  // attention: grid (bh, qt) — one q-tile per block, longest first
  attn_kernel<<<dim3(BATCH * NH, 32), 256, 0, stream>>>(Qp, Kp, Vt, attn);

  dim3 gg(MTOT / 64, 4);
  // h = attn @ Wo + bo + q
  gemm_kernel<EPI_F32RES><<<gg, 256, 0, stream>>>(attn, Wt + 3 * 512 * 512, bo, q_in, hy);
  ln_kernel<1><<<MTOT / 4, 256, 0, stream>>>(hy, g1, be1, ln1f, ln1b);
  // f1 = leaky(ln1 @ Wh + bh)
  gemm_kernel<EPI_LRELU><<<gg, 256, 0, stream>>>(ln1b, Wt + 4 * 512 * 512, bh, nullptr, f1);
  // y = f1 @ W2 + b2 + ln1
  gemm_kernel<EPI_F32RES><<<gg, 256, 0, stream>>>(f1, Wt + 5 * 512 * 512, b2, ln1f, hy);
  ln_kernel<0><<<MTOT / 4, 256, 0, stream>>>(hy, g2, be2, (float*)d_out, nullptr);
}